// Round 10
// baseline (629.108 us; speedup 1.0000x reference)
//
#include <hip/hip_runtime.h>
#include <hip/hip_bf16.h>

#define BQ 16
#define CH 192
#define HH 64
#define WW 64
#define HWSZ 4096
#define NPIX 65536
#define NHEADS 6
#define HDIM 32
#define NPAIR 96
#define KMAXR 48
#define HID 768

typedef __hip_bfloat16 bf16;
typedef __attribute__((ext_vector_type(8))) short short8;
typedef __attribute__((ext_vector_type(4))) float floatx4;

static __device__ __forceinline__ float b2f(bf16 v) { return __bfloat162float(v); }
static __device__ __forceinline__ bf16 f2b(float v) { return __float2bfloat16(v); }

static __device__ __forceinline__ float4 ld4(const float* p) { return *(const float4*)p; }
static __device__ __forceinline__ float4 ld4(const bf16* p) {
  uint2 u = *(const uint2*)p;
  return make_float4(__uint_as_float(u.x << 16), __uint_as_float(u.x & 0xffff0000u),
                     __uint_as_float(u.y << 16), __uint_as_float(u.y & 0xffff0000u));
}

template <int ACT>
static __device__ __forceinline__ float actf(float v) {
  if (ACT == 1) return v / (1.f + expf(-v));                               // silu
  if (ACT == 2) return (v > 0.f) ? v + 1.f : expf(v);                      // elu+1
  if (ACT == 3) return 0.5f * v * (1.f + erff(v * 0.70710678118654752f));  // gelu
  return v;
}
static __device__ __forceinline__ void stv(float* p, float v) { *p = v; }
static __device__ __forceinline__ void stv(bf16* p, float v) { *p = __float2bfloat16(v); }

// ---------------- transpose NCHW -> NHWC (fp32) ----------------
__global__ __launch_bounds__(256) void k_transpose_in(const float* __restrict__ in,
                                                      float* __restrict__ out) {
  __shared__ float tile[32][33];
  int c0 = blockIdx.x * 32, hw0 = blockIdx.y * 32, b = blockIdx.z;
  int tx = threadIdx.x, ty = threadIdx.y;
  const float* src = in + (size_t)b * CH * HWSZ;
  #pragma unroll
  for (int j = 0; j < 32; j += 8)
    tile[ty + j][tx] = src[(size_t)(c0 + ty + j) * HWSZ + hw0 + tx];
  __syncthreads();
  float* dst = out + (size_t)b * HWSZ * CH;
  #pragma unroll
  for (int j = 0; j < 32; j += 8)
    dst[(size_t)(hw0 + ty + j) * CH + c0 + tx] = tile[tx][ty + j];
}

// ---------------- transpose NHWC -> NCHW (fp32) ----------------
__global__ __launch_bounds__(256) void k_transpose_out(const float* __restrict__ in,
                                                       float* __restrict__ out) {
  __shared__ float tile[32][33];
  int c0 = blockIdx.x * 32, hw0 = blockIdx.y * 32, b = blockIdx.z;
  int tx = threadIdx.x, ty = threadIdx.y;
  const float* src = in + (size_t)b * HWSZ * CH;
  #pragma unroll
  for (int j = 0; j < 32; j += 8)
    tile[ty + j][tx] = src[(size_t)(hw0 + ty + j) * CH + c0 + tx];
  __syncthreads();
  float* dst = out + (size_t)b * CH * HWSZ;
  #pragma unroll
  for (int j = 0; j < 32; j += 8)
    dst[(size_t)(c0 + ty + j) * HWSZ + hw0 + tx] = tile[tx][ty + j];
}

// ---------------- RoPE tables, layout [pair][hw] ----------------
__global__ __launch_bounds__(256) void k_rope(float* __restrict__ cosT, float* __restrict__ sinT) {
  int i = blockIdx.x * 256 + threadIdx.x;
  if (i >= NPAIR * HWSZ) return;
  int hw = i & (HWSZ - 1);
  int p = i >> 12;
  int h = hw >> 6, w = hw & 63;
  int j = (p < KMAXR) ? p : p - KMAXR;
  float theta = powf(10000.f, -(float)j / (float)KMAXR);
  float pos = (p < KMAXR) ? (float)h : (float)w;
  float ang = pos * theta;
  cosT[i] = cosf(ang);
  sinT[i] = sinf(ang);
}

// ---------------- one-shot fp32 -> bf16 weight conversion ----------------
// regions (element offsets): ap 0, ip 36864, qk 73728, op 147456, f1 184320, f2 331776
#define WTOT 479232
__global__ __launch_bounds__(256) void k_wcvt(const float* __restrict__ ap,
                                              const float* __restrict__ ip,
                                              const float* __restrict__ qk,
                                              const float* __restrict__ op,
                                              const float* __restrict__ f1,
                                              const float* __restrict__ f2,
                                              bf16* __restrict__ o) {
  int i = (blockIdx.x * 256 + threadIdx.x) * 4;
  if (i >= WTOT) return;
  const float* src;
  int off;
  if (i < 36864)       { src = ap; off = 0; }
  else if (i < 73728)  { src = ip; off = 36864; }
  else if (i < 147456) { src = qk; off = 73728; }
  else if (i < 184320) { src = op; off = 147456; }
  else if (i < 331776) { src = f1; off = 184320; }
  else                 { src = f2; off = 331776; }
  float4 v = ld4(src + (i - off));
  __align__(8) bf16 t4[4] = {f2b(v.x), f2b(v.y), f2b(v.z), f2b(v.w)};
  *(uint2*)&o[i] = *(uint2*)t4;
}

// ---------------- fused dwconv(residual) + LayerNorm (strip) ----------------
template <typename TI>
__global__ __launch_bounds__(192) void k_cpe_ln(const TI* __restrict__ in,
                                                const float* __restrict__ w,
                                                const float* __restrict__ bias,
                                                const float* __restrict__ g,
                                                const float* __restrict__ bt,
                                                float* __restrict__ x1o,
                                                bf16* __restrict__ yo) {
  __shared__ float grs[12][4], grq[12][4];
  int t = threadIdx.x;
  int cg = t % 48, st = t / 48;
  int c0 = cg * 4;
  int gpix = blockIdx.x * 16 + st * 4;  // first pixel of this strip (incl. batch)
  int hw = gpix & (HWSZ - 1);
  int h = hw >> 6, wx = hw & 63;        // strip covers cols wx..wx+3 of row h
  float4 w4[9];
  #pragma unroll
  for (int i = 0; i < 9; i++) w4[i] = ld4(w + c0 * 9 + i * 4);
  const float* wf = (const float*)w4;
  float4 bi = ld4(bias + c0);
  float4 acc[4];
  #pragma unroll
  for (int i = 0; i < 4; i++) acc[i] = bi;
  const TI* base = in + (size_t)gpix * CH + c0;
  #pragma unroll
  for (int dh = -1; dh <= 1; dh++) {
    bool rv = ((unsigned)(h + dh) < HH);
    float4 tap[6];
    #pragma unroll
    for (int c = 0; c < 6; c++) {
      int col = wx - 1 + c;
      bool v = rv && ((unsigned)col < WW);
      tap[c] = v ? ld4(base + (dh * WW + (c - 1)) * CH) : make_float4(0, 0, 0, 0);
    }
    #pragma unroll
    for (int i = 0; i < 4; i++) {
      #pragma unroll
      for (int dw = 0; dw < 3; dw++) {
        const int tp = (dh + 1) * 3 + dw;
        float4 tv = tap[i + dw];
        acc[i].x += tv.x * wf[0 * 9 + tp];
        acc[i].y += tv.y * wf[1 * 9 + tp];
        acc[i].z += tv.z * wf[2 * 9 + tp];
        acc[i].w += tv.w * wf[3 * 9 + tp];
      }
      if (dh == 0) {  // residual: x + conv(x)
        acc[i].x += tap[i + 1].x;
        acc[i].y += tap[i + 1].y;
        acc[i].z += tap[i + 1].z;
        acc[i].w += tap[i + 1].w;
      }
    }
  }
  float s4[4], q4[4];
  #pragma unroll
  for (int i = 0; i < 4; i++) {
    *(float4*)&x1o[(size_t)(gpix + i) * CH + c0] = acc[i];
    s4[i] = acc[i].x + acc[i].y + acc[i].z + acc[i].w;
    q4[i] = acc[i].x * acc[i].x + acc[i].y * acc[i].y + acc[i].z * acc[i].z +
            acc[i].w * acc[i].w;
  }
  #pragma unroll
  for (int m = 1; m <= 8; m <<= 1) {
    #pragma unroll
    for (int i = 0; i < 4; i++) {
      s4[i] += __shfl_xor(s4[i], m, 64);
      q4[i] += __shfl_xor(q4[i], m, 64);
    }
  }
  if ((t & 15) == 0) {
    #pragma unroll
    for (int i = 0; i < 4; i++) { grs[t >> 4][i] = s4[i]; grq[t >> 4][i] = q4[i]; }
  }
  __syncthreads();
  int s3 = st * 3;
  float4 gg = ld4(g + c0);
  float4 bb = ld4(bt + c0);
  #pragma unroll
  for (int i = 0; i < 4; i++) {
    float S = grs[s3][i] + grs[s3 + 1][i] + grs[s3 + 2][i];
    float SS = grq[s3][i] + grq[s3 + 1][i] + grq[s3 + 2][i];
    float mu = S * (1.f / CH);
    float inv = rsqrtf(SS * (1.f / CH) - mu * mu + 1e-5f);
    __align__(8) bf16 tmp[4] = {f2b((acc[i].x - mu) * inv * gg.x + bb.x),
                                f2b((acc[i].y - mu) * inv * gg.y + bb.y),
                                f2b((acc[i].z - mu) * inv * gg.z + bb.z),
                                f2b((acc[i].w - mu) * inv * gg.w + bb.w)};
    *(uint2*)&yo[(size_t)(gpix + i) * CH + c0] = *(uint2*)tmp;
  }
}

// ---------------- strip dwconv, bf16 in/out, 4ch x 4 pixels per thread ----------------
// MODE 1: out = silu(conv+bias)   MODE 2: out += conv+bias
template <int MODE>
__global__ __launch_bounds__(192) void k_dwconv_strip(const bf16* __restrict__ in,
                                                      const float* __restrict__ w,
                                                      const float* __restrict__ bias,
                                                      bf16* __restrict__ out) {
  int t = threadIdx.x;
  int cg = t % 48, st = t / 48;
  int c0 = cg * 4;
  int gpix = blockIdx.x * 16 + st * 4;
  int hw = gpix & (HWSZ - 1);
  int h = hw >> 6, wx = hw & 63;
  float4 w4[9];
  #pragma unroll
  for (int i = 0; i < 9; i++) w4[i] = ld4(w + c0 * 9 + i * 4);
  const float* wf = (const float*)w4;
  float4 bi = ld4(bias + c0);
  float4 acc[4];
  #pragma unroll
  for (int i = 0; i < 4; i++) acc[i] = bi;
  const bf16* base = in + (size_t)gpix * CH + c0;
  #pragma unroll
  for (int dh = -1; dh <= 1; dh++) {
    bool rv = ((unsigned)(h + dh) < HH);
    float4 tap[6];
    #pragma unroll
    for (int c = 0; c < 6; c++) {
      int col = wx - 1 + c;
      bool v = rv && ((unsigned)col < WW);
      tap[c] = v ? ld4(base + (dh * WW + (c - 1)) * CH) : make_float4(0, 0, 0, 0);
    }
    #pragma unroll
    for (int i = 0; i < 4; i++) {
      #pragma unroll
      for (int dw = 0; dw < 3; dw++) {
        const int tp = (dh + 1) * 3 + dw;
        float4 tv = tap[i + dw];
        acc[i].x += tv.x * wf[0 * 9 + tp];
        acc[i].y += tv.y * wf[1 * 9 + tp];
        acc[i].z += tv.z * wf[2 * 9 + tp];
        acc[i].w += tv.w * wf[3 * 9 + tp];
      }
    }
  }
  #pragma unroll
  for (int i = 0; i < 4; i++) {
    bf16* op = out + (size_t)(gpix + i) * CH + c0;
    float a0 = acc[i].x, a1 = acc[i].y, a2 = acc[i].z, a3 = acc[i].w;
    if (MODE == 1) {
      a0 = a0 / (1.f + expf(-a0));
      a1 = a1 / (1.f + expf(-a1));
      a2 = a2 / (1.f + expf(-a2));
      a3 = a3 / (1.f + expf(-a3));
    } else {
      float4 cur = ld4(op);
      a0 += cur.x; a1 += cur.y; a2 += cur.z; a3 += cur.w;
    }
    __align__(8) bf16 tmp[4] = {f2b(a0), f2b(a1), f2b(a2), f2b(a3)};
    *(uint2*)op = *(uint2*)tmp;
  }
}

// ---------------- MFMA bf16 GEMM: tile 128x64, BK=64, 27.6KB LDS ----------------
// BK=64 -> 4 blocks/CU resident; proven round-7 epilogue (scattered stores).
template <int ACT, int MULA, int RES, typename TO>
__global__ __launch_bounds__(256) void k_gemm(const bf16* __restrict__ A,
                                              const bf16* __restrict__ A2,
                                              const bf16* __restrict__ Wt,
                                              const float* __restrict__ bias,
                                              const float* __restrict__ Rsd,
                                              TO* __restrict__ Cout,
                                              int M, int N, int K) {
  __shared__ bf16 As[128][72];
  __shared__ bf16 Bs[64][72];
  int t = threadIdx.x;
  int wave = t >> 6, lane = t & 63;
  int quad = lane >> 4, l16 = lane & 15;
  int m0 = blockIdx.x * 128, n0 = blockIdx.y * 64;
  floatx4 acc[2][4] = {};
  for (int kc = 0; kc < K; kc += 64) {
    #pragma unroll
    for (int i = 0; i < 4; i++) {
      int idx = t + i * 256;
      int m = idx >> 3, ck = (idx & 7) * 8;
      const bf16* pa = &A[(size_t)(m0 + m) * K + kc + ck];
      if (!MULA) {
        *(short8*)&As[m][ck] = *(const short8*)pa;
      } else {
        const bf16* pb = &A2[(size_t)(m0 + m) * K + kc + ck];
        __align__(16) bf16 tmp[8];
        #pragma unroll
        for (int j = 0; j < 8; j++) tmp[j] = f2b(b2f(pa[j]) * b2f(pb[j]));
        *(short8*)&As[m][ck] = *(const short8*)tmp;
      }
    }
    #pragma unroll
    for (int i = 0; i < 2; i++) {
      int idx = t + i * 256;
      int n = idx >> 3, ck = (idx & 7) * 8;
      *(short8*)&Bs[n][ck] = *(const short8*)&Wt[(size_t)(n0 + n) * K + kc + ck];
    }
    __syncthreads();
    #pragma unroll
    for (int ks = 0; ks < 2; ks++) {
      short8 af[2], bfr[4];
      #pragma unroll
      for (int i = 0; i < 2; i++)
        af[i] = *(const short8*)&As[wave * 32 + i * 16 + l16][ks * 32 + quad * 8];
      #pragma unroll
      for (int j = 0; j < 4; j++)
        bfr[j] = *(const short8*)&Bs[j * 16 + l16][ks * 32 + quad * 8];
      #pragma unroll
      for (int i = 0; i < 2; i++)
        #pragma unroll
        for (int j = 0; j < 4; j++)
          acc[i][j] = __builtin_amdgcn_mfma_f32_16x16x32_bf16(af[i], bfr[j], acc[i][j], 0, 0, 0);
    }
    __syncthreads();
  }
  #pragma unroll
  for (int i = 0; i < 2; i++) {
    #pragma unroll
    for (int j = 0; j < 4; j++) {
      int n = n0 + j * 16 + l16;
      float bn = bias[n];
      #pragma unroll
      for (int r = 0; r < 4; r++) {
        int m = m0 + wave * 32 + i * 16 + quad * 4 + r;
        float v = actf<ACT>(acc[i][j][r] + bn);
        if (RES) v += Rsd[(size_t)m * N + n];
        stv(&Cout[(size_t)m * N + n], v);
      }
    }
  }
}

// dual-output GEMM (K=192, BK=64): N=384 as two 192 halves; optional fused col-mean of half B.
template <int ACTA, int ACTB, int KMEAN>
__global__ __launch_bounds__(256) void k_gemm_dual(const bf16* __restrict__ A,
                                                   const bf16* __restrict__ WtA,
                                                   const float* __restrict__ biasA,
                                                   const bf16* __restrict__ WtB,
                                                   const float* __restrict__ biasB,
                                                   bf16* __restrict__ OutA,
                                                   bf16* __restrict__ OutB,
                                                   float* __restrict__ KM,
                                                   int K) {
  __shared__ bf16 As[128][72];
  __shared__ bf16 Bs[64][72];
  __shared__ float colsum[64];
  int t = threadIdx.x;
  int wave = t >> 6, lane = t & 63;
  int quad = lane >> 4, l16 = lane & 15;
  int m0 = blockIdx.x * 128, n0 = blockIdx.y * 64;
  int half = n0 >= 192;
  int n0l = half ? n0 - 192 : n0;
  const bf16* Wt = half ? WtB : WtA;
  const float* bias = half ? biasB : biasA;
  bf16* Out = half ? OutB : OutA;
  if (KMEAN && half && t < 64) colsum[t] = 0.f;
  floatx4 acc[2][4] = {};
  for (int kc = 0; kc < CH; kc += 64) {
    #pragma unroll
    for (int i = 0; i < 4; i++) {
      int idx = t + i * 256;
      int m = idx >> 3, ck = (idx & 7) * 8;
      *(short8*)&As[m][ck] = *(const short8*)&A[(size_t)(m0 + m) * CH + kc + ck];
    }
    #pragma unroll
    for (int i = 0; i < 2; i++) {
      int idx = t + i * 256;
      int n = idx >> 3, ck = (idx & 7) * 8;
      *(short8*)&Bs[n][ck] = *(const short8*)&Wt[(size_t)(n0l + n) * CH + kc + ck];
    }
    __syncthreads();
    #pragma unroll
    for (int ks = 0; ks < 2; ks++) {
      short8 af[2], bfr[4];
      #pragma unroll
      for (int i = 0; i < 2; i++)
        af[i] = *(const short8*)&As[wave * 32 + i * 16 + l16][ks * 32 + quad * 8];
      #pragma unroll
      for (int j = 0; j < 4; j++)
        bfr[j] = *(const short8*)&Bs[j * 16 + l16][ks * 32 + quad * 8];
      #pragma unroll
      for (int i = 0; i < 2; i++)
        #pragma unroll
        for (int j = 0; j < 4; j++)
          acc[i][j] = __builtin_amdgcn_mfma_f32_16x16x32_bf16(af[i], bfr[j], acc[i][j], 0, 0, 0);
    }
    __syncthreads();
  }
  #pragma unroll
  for (int j = 0; j < 4; j++) {
    int nl = n0l + j * 16 + l16;
    float bn = bias[nl];
    float csum = 0.f;
    #pragma unroll
    for (int i = 0; i < 2; i++) {
      #pragma unroll
      for (int r = 0; r < 4; r++) {
        int m = m0 + wave * 32 + i * 16 + quad * 4 + r;
        float v = half ? actf<ACTB>(acc[i][j][r] + bn) : actf<ACTA>(acc[i][j][r] + bn);
        if (KMEAN && half) csum += v;
        Out[(size_t)m * CH + nl] = f2b(v);
      }
    }
    if (KMEAN && half) atomicAdd(&colsum[j * 16 + l16], csum);
  }
  if (KMEAN && half) {
    __syncthreads();
    if (t < 64) {
      int b = m0 >> 12;
      atomicAdd(&KM[b * CH + n0l + t], colsum[t] * (1.f / 4096.f));
    }
  }
}

// ---------------- fused MLP: out += fc2(gelu(fc1(y))) ----------------
// One block = 128 pixels. Loop 12 hidden-chunks of 64: fc1 (3 BK=64 ksteps) -> gelu ->
// restage bf16 hidden through Hs -> fc2 partial accumulate (N=192, 12 n-tiles).
// Kills the 200MB hidden-tensor HBM round trip (fc1-write + fc2-read).
// fc2 k-chunk order == old BK=64 fc2 -> identical partial-sum order (same numerics).
// LDS 66KB -> 2 blocks/CU.
__global__ __launch_bounds__(256) void k_mlp(const bf16* __restrict__ Y,
                                             const bf16* __restrict__ W1,
                                             const float* __restrict__ B1,
                                             const bf16* __restrict__ W2,
                                             const float* __restrict__ B2,
                                             float* __restrict__ XR) {
  __shared__ bf16 As[128][72];
  __shared__ bf16 Bs[192][72];
  __shared__ bf16 Hs[128][80];
  int t = threadIdx.x;
  int wave = t >> 6, lane = t & 63;
  int quad = lane >> 4, l16 = lane & 15;
  int m0 = blockIdx.x * 128;
  floatx4 acc2[2][12] = {};
  for (int hc = 0; hc < 12; hc++) {
    int h0 = hc * 64;
    floatx4 acc1[2][4] = {};
    for (int ks3 = 0; ks3 < 3; ks3++) {
      int kc = ks3 * 64;
      #pragma unroll
      for (int i = 0; i < 4; i++) {
        int idx = t + i * 256;
        int m = idx >> 3, ck = (idx & 7) * 8;
        *(short8*)&As[m][ck] = *(const short8*)&Y[(size_t)(m0 + m) * CH + kc + ck];
      }
      #pragma unroll
      for (int i = 0; i < 2; i++) {
        int idx = t + i * 256;
        int n = idx >> 3, ck = (idx & 7) * 8;
        *(short8*)&Bs[n][ck] = *(const short8*)&W1[(size_t)(h0 + n) * CH + kc + ck];
      }
      __syncthreads();
      #pragma unroll
      for (int ks = 0; ks < 2; ks++) {
        short8 af[2], bfr[4];
        #pragma unroll
        for (int i = 0; i < 2; i++)
          af[i] = *(const short8*)&As[wave * 32 + i * 16 + l16][ks * 32 + quad * 8];
        #pragma unroll
        for (int j = 0; j < 4; j++)
          bfr[j] = *(const short8*)&Bs[j * 16 + l16][ks * 32 + quad * 8];
        #pragma unroll
        for (int i = 0; i < 2; i++)
          #pragma unroll
          for (int j = 0; j < 4; j++)
            acc1[i][j] = __builtin_amdgcn_mfma_f32_16x16x32_bf16(af[i], bfr[j], acc1[i][j], 0, 0, 0);
      }
      __syncthreads();
    }
    // gelu(acc1 + b1) -> Hs (bf16), C/D layout col=lane&15, row=quad*4+r
    #pragma unroll
    for (int j = 0; j < 4; j++) {
      int col = j * 16 + l16;
      float bn = B1[h0 + col];
      #pragma unroll
      for (int i = 0; i < 2; i++) {
        #pragma unroll
        for (int r = 0; r < 4; r++) {
          int row = wave * 32 + i * 16 + quad * 4 + r;
          float v = acc1[i][j][r] + bn;
          Hs[row][col] = f2b(0.5f * v * (1.f + erff(v * 0.70710678118654752f)));
        }
      }
    }
    // stage W2 chunk: Bs[n out][ck h]  (Bs1 rows dead since last fc1 barrier)
    #pragma unroll
    for (int i = 0; i < 6; i++) {
      int idx = t + i * 256;
      int n = idx >> 3, ck = (idx & 7) * 8;
      *(short8*)&Bs[n][ck] = *(const short8*)&W2[(size_t)n * HID + h0 + ck];
    }
    __syncthreads();
    #pragma unroll
    for (int ks = 0; ks < 2; ks++) {
      short8 af[2];
      #pragma unroll
      for (int i = 0; i < 2; i++)
        af[i] = *(const short8*)&Hs[wave * 32 + i * 16 + l16][ks * 32 + quad * 8];
      #pragma unroll
      for (int j = 0; j < 12; j++) {
        short8 bfr = *(const short8*)&Bs[j * 16 + l16][ks * 32 + quad * 8];
        #pragma unroll
        for (int i = 0; i < 2; i++)
          acc2[i][j] = __builtin_amdgcn_mfma_f32_16x16x32_bf16(af[i], bfr, acc2[i][j], 0, 0, 0);
      }
    }
    __syncthreads();  // fc2 reads done before next chunk overwrites As/Bs/Hs
  }
  // epilogue: out = acc2 + b2 + residual (XR fp32, read-modify-write)
  #pragma unroll
  for (int j = 0; j < 12; j++) {
    int n = j * 16 + l16;
    float bn = B2[n];
    #pragma unroll
    for (int i = 0; i < 2; i++) {
      #pragma unroll
      for (int r = 0; r < 4; r++) {
        int m = m0 + wave * 32 + i * 16 + quad * 4 + r;
        float* p = &XR[(size_t)m * CH + n];
        *p = acc2[i][j][r] + bn + *p;
      }
    }
  }
}

// ---------------- kv via MFMA: kv[d][e] = sum_n K_rope[n][d] * V[n][e] ----------------
__global__ __launch_bounds__(256) void k_kv(const bf16* __restrict__ k,
                                            const bf16* __restrict__ v,
                                            const float* __restrict__ cosT,
                                            const float* __restrict__ sinT,
                                            float* __restrict__ kv) {
  int bh = blockIdx.x;
  int b = bh / NHEADS, hd = bh % NHEADS;
  int chunk0 = blockIdx.y * 512;
  __shared__ __align__(16) bf16 kst[32][280];
  __shared__ __align__(16) bf16 vst[32][280];
  int t = threadIdx.x;
  int wave = t >> 6, lane = t & 63;
  int quad = lane >> 4, l16 = lane & 15;
  int dh = wave >> 1, eh = wave & 1;
  floatx4 acc = {};
  for (int sub = 0; sub < 2; sub++) {
    int n0 = chunk0 + sub * 256;
    #pragma unroll
    for (int it = 0; it < 4; it++) {
      int idx = t + it * 256;            // 0..1023 = 256 rows x 4 c-groups
      int row = idx >> 2, c0 = (idx & 3) * 8;
      int n = n0 + row;
      size_t gi = ((size_t)(b * HWSZ + n)) * CH + hd * HDIM + c0;
      short8 vv = *(const short8*)&v[gi];
      #pragma unroll
      for (int j = 0; j < 8; j++) vst[c0 + j][row] = ((const bf16*)&vv)[j];
      float4 klo = ld4(&k[gi]);
      float4 khi = ld4(&k[gi + 4]);
      int prb = hd * 16 + (c0 >> 1);
      float cs0 = cosT[(size_t)(prb + 0) * HWSZ + n];
      float sn0 = sinT[(size_t)(prb + 0) * HWSZ + n];
      float cs1 = cosT[(size_t)(prb + 1) * HWSZ + n];
      float sn1 = sinT[(size_t)(prb + 1) * HWSZ + n];
      float cs2 = cosT[(size_t)(prb + 2) * HWSZ + n];
      float sn2 = sinT[(size_t)(prb + 2) * HWSZ + n];
      float cs3 = cosT[(size_t)(prb + 3) * HWSZ + n];
      float sn3 = sinT[(size_t)(prb + 3) * HWSZ + n];
      kst[c0 + 0][row] = f2b(klo.x * cs0 - klo.y * sn0);
      kst[c0 + 1][row] = f2b(klo.x * sn0 + klo.y * cs0);
      kst[c0 + 2][row] = f2b(klo.z * cs1 - klo.w * sn1);
      kst[c0 + 3][row] = f2b(klo.z * sn1 + klo.w * cs1);
      kst[c0 + 4][row] = f2b(khi.x * cs2 - khi.y * sn2);
      kst[c0 + 5][row] = f2b(khi.x * sn2 + khi.y * cs2);
      kst[c0 + 6][row] = f2b(khi.z * cs3 - khi.w * sn3);
      kst[c0 + 7][row] = f2b(khi.z * sn3 + khi.w * cs3);
    }
    __syncthreads();
    #pragma unroll
    for (int ks = 0; ks < 8; ks++) {
      short8 af = *(const short8*)&kst[dh * 16 + l16][ks * 32 + quad * 8];
      short8 bfr = *(const short8*)&vst[eh * 16 + l16][ks * 32 + quad * 8];
      acc = __builtin_amdgcn_mfma_f32_16x16x32_bf16(af, bfr, acc, 0, 0, 0);
    }
    __syncthreads();
  }
  // C/D layout: col = lane&15, row = quad*4 + r  (m89-verified)
  int d = dh * 16 + quad * 4;
  int e = eh * 16 + l16;
  float* dst = kv + (size_t)bh * (HDIM * HDIM) + (size_t)d * HDIM + e;
  const float sc = 1.f / 4096.f;
  #pragma unroll
  for (int r = 0; r < 4; r++) atomicAdd(dst + r * HDIM, acc[r] * sc);
}

// ---------------- attn via MFMA: out = (rope(q) @ kv) * zi ----------------
__global__ __launch_bounds__(256) void k_attn(const bf16* __restrict__ q,
                                              const float* __restrict__ kv,
                                              const float* __restrict__ kmean,
                                              const float* __restrict__ cosT,
                                              const float* __restrict__ sinT,
                                              bf16* __restrict__ attn) {
  int hd = blockIdx.y, b = blockIdx.z;
  int t = threadIdx.x;
  int hw = blockIdx.x * 256 + t;
  int bh = b * NHEADS + hd;
  __shared__ __align__(16) bf16 As[256][40];
  __shared__ __align__(16) bf16 Bs[32][40];
  int wave = t >> 6, lane = t & 63;
  int quad = lane >> 4, l16 = lane & 15;
  // stage kv^T -> Bs[e][d] (bf16)
  {
    int e = t >> 3, d0 = (t & 7) * 4;
    const float* kvp = kv + (size_t)bh * 1024;
    __align__(8) bf16 tmp[4] = {f2b(kvp[(d0 + 0) * 32 + e]), f2b(kvp[(d0 + 1) * 32 + e]),
                                f2b(kvp[(d0 + 2) * 32 + e]), f2b(kvp[(d0 + 3) * 32 + e])};
    *(uint2*)&Bs[e][d0] = *(uint2*)tmp;
  }
  // per-pixel: z (pre-rope) and rope(q) -> As[t][:]
  int pix = b * HWSZ + hw;
  const bf16* qp = q + (size_t)pix * CH + hd * HDIM;
  float qv[32];
  #pragma unroll
  for (int i = 0; i < 32; i++) qv[i] = b2f(qp[i]);
  const float* km = kmean + b * CH + hd * HDIM;
  float z = 1e-6f;
  #pragma unroll
  for (int d = 0; d < 32; d++) z += qv[d] * km[d];
  float zi = 1.f / z;
  __align__(16) bf16 ar[32];
  #pragma unroll
  for (int p = 0; p < 16; p++) {
    float cs = cosT[(size_t)(hd * 16 + p) * HWSZ + hw];
    float sn = sinT[(size_t)(hd * 16 + p) * HWSZ + hw];
    float re = qv[2 * p], im = qv[2 * p + 1];
    ar[2 * p] = f2b(re * cs - im * sn);
    ar[2 * p + 1] = f2b(re * sn + im * cs);
  }
  #pragma unroll
  for (int i = 0; i < 4; i++) *(short8*)&As[t][i * 8] = *(const short8*)&ar[i * 8];
  __syncthreads();
  // MFMA: wave w owns pixels [w*64, w*64+64): 4 m-tiles x 2 n-tiles
  short8 af[4], bfr[2];
  #pragma unroll
  for (int nt = 0; nt < 2; nt++) bfr[nt] = *(const short8*)&Bs[nt * 16 + l16][quad * 8];
  #pragma unroll
  for (int mt = 0; mt < 4; mt++)
    af[mt] = *(const short8*)&As[wave * 64 + mt * 16 + l16][quad * 8];
  floatx4 acc[4][2] = {};
  #pragma unroll
  for (int mt = 0; mt < 4; mt++)
    #pragma unroll
    for (int nt = 0; nt < 2; nt++)
      acc[mt][nt] = __builtin_amdgcn_mfma_f32_16x16x32_bf16(af[mt], bfr[nt], acc[mt][nt], 0, 0, 0);
  __syncthreads();
  // C restage into As: row = pixel (wave-local), col = e
  #pragma unroll
  for (int mt = 0; mt < 4; mt++)
    #pragma unroll
    for (int nt = 0; nt < 2; nt++) {
      int row = wave * 64 + mt * 16 + quad * 4;
      int col = nt * 16 + l16;
      #pragma unroll
      for (int r = 0; r < 4; r++) As[row + r][col] = f2b(acc[mt][nt][r]);
    }
  __syncthreads();
  // each thread: read its own pixel row, scale by in-register zi, coalesced store
  bf16* op = attn + (size_t)pix * CH + hd * HDIM;
  #pragma unroll
  for (int i = 0; i < 4; i++) {
    short8 vv = *(const short8*)&As[t][i * 8];
    __align__(16) bf16 tmp[8];
    #pragma unroll
    for (int j = 0; j < 8; j++) tmp[j] = f2b(b2f(((const bf16*)&vv)[j]) * zi);
    *(short8*)&op[i * 8] = *(const short8*)tmp;
  }
}

extern "C" void kernel_launch(void* const* d_in, const int* in_sizes, int n_in,
                              void* d_out, int out_size, void* d_ws, size_t ws_size,
                              hipStream_t stream) {
  const float* x = (const float*)d_in[0];
  const float* cpe1w = (const float*)d_in[1];
  const float* cpe1b = (const float*)d_in[2];
  const float* n1w = (const float*)d_in[3];
  const float* n1b = (const float*)d_in[4];
  const float* apw = (const float*)d_in[5];
  const float* apb = (const float*)d_in[6];
  const float* ipw = (const float*)d_in[7];
  const float* ipb = (const float*)d_in[8];
  const float* dwcw = (const float*)d_in[9];
  const float* dwcb = (const float*)d_in[10];
  const float* qkw = (const float*)d_in[11];
  const float* qkb = (const float*)d_in[12];
  const float* lepw = (const float*)d_in[13];
  const float* lepb = (const float*)d_in[14];
  const float* opw = (const float*)d_in[15];
  const float* opb = (const float*)d_in[16];
  const float* cpe2w = (const float*)d_in[17];
  const float* cpe2b = (const float*)d_in[18];
  const float* n2w = (const float*)d_in[19];
  const float* n2b = (const float*)d_in[20];
  const float* f1w = (const float*)d_in[21];
  const float* f1b = (const float*)d_in[22];
  const float* f2w = (const float*)d_in[23];
  const float* f2b = (const float*)d_in[24];
  float* out = (float*)d_out;

  float* ws = (float*)d_ws;
  const size_t S = (size_t)NPIX * CH;
  float* FA = ws;                       // fp32: x NHWC -> (bf16 k/attn scratch) -> x3 -> final
  float* FB = ws + S;                   // fp32: x1
  bf16* barena = (bf16*)(ws + 2 * S);
  bf16* b0 = barena;                    // y -> t/v -> y4
  bf16* b1 = barena + S;                // act_res
  bf16* b2 = barena + 2 * S;            // y2 -> q -> x2
  bf16* KB = (bf16*)FA;                 // k, then attn (FA dead between cpe1 and cpe2)
  float* COS = ws + 2 * S + 3 * S / 2;
  float* SIN = COS + (size_t)NPAIR * HWSZ;
  float* KV = SIN + (size_t)NPAIR * HWSZ;
  float* KM = KV + BQ * NHEADS * HDIM * HDIM;
  bf16* WB = (bf16*)(KM + BQ * CH);     // bf16 weight arena (479232 elems)
  bf16* apw16 = WB;
  bf16* ipw16 = WB + 36864;
  bf16* qkw16 = WB + 73728;             // [384][192]; halves at +0 and +36864
  bf16* opw16 = WB + 147456;
  bf16* f1w16 = WB + 184320;
  bf16* f2w16 = WB + 331776;

  dim3 tb(32, 8);
  // 0. weights -> bf16 once
  k_wcvt<<<dim3((WTOT / 4 + 255) / 256), dim3(256), 0, stream>>>(
      apw, ipw, qkw, opw, f1w, f2w, WB);
  // 1. transpose input NCHW -> NHWC fp32
  k_transpose_in<<<dim3(6, 128, BQ), tb, 0, stream>>>(x, FA);
  // 2. rope tables [pair][hw]
  k_rope<<<dim3(NPAIR * HWSZ / 256), dim3(256), 0, stream>>>(COS, SIN);
  // 3. x1 = x + cpe1(x); y = LN1(x1)   [fused]
  k_cpe_ln<float><<<dim3(NPIX / 16), dim3(192), 0, stream>>>(FA, cpe1w, cpe1b, n1w, n1b, FB, b0);
  // 4. act_res = silu(act_proj(y)); y2 = in_proj(y)
  k_gemm_dual<1, 0, 0><<<dim3(NPIX / 128, 6), dim3(256), 0, stream>>>(
      b0, apw16, apb, ipw16, ipb, b1, b2, nullptr, CH);
  // 5. t = v = silu(dwc(y2))
  k_dwconv_strip<1><<<dim3(NPIX / 16), dim3(192), 0, stream>>>(b2, dwcw, dwcb, b0);
  // 6. q,k = elu(t @ qk_w^T + qk_b)+1 ; kmean fused into k epilogue
  hipMemsetAsync(KM, 0, (size_t)BQ * CH * sizeof(float), stream);
  k_gemm_dual<2, 2, 1><<<dim3(NPIX / 128, 6), dim3(256), 0, stream>>>(
      b0, qkw16, qkb, qkw16 + CH * CH, qkb + CH, b2, KB, KM, CH);
  // 7. kv accumulate (fused rope, MFMA, 512 rows/block)
  hipMemsetAsync(KV, 0, (size_t)BQ * NHEADS * HDIM * HDIM * sizeof(float), stream);
  k_kv<<<dim3(BQ * NHEADS, 8), dim3(256), 0, stream>>>(KB, b0, COS, SIN, KV);
  // 8. attn = (q_rope @ kv) * z  -> KB (k dead)
  k_attn<<<dim3(HWSZ / 256, NHEADS, BQ), dim3(256), 0, stream>>>(b2, KV, KM, COS, SIN, KB);
  // 9. attn += lepe(v)
  k_dwconv_strip<2><<<dim3(NPIX / 16), dim3(192), 0, stream>>>(b0, lepw, lepb, KB);
  // 10. x2 = x1 + out_proj(attn * act_res)  -> b2 (bf16)
  k_gemm<0, 1, 1, bf16><<<dim3(NPIX / 128, 3), dim3(256), 0, stream>>>(
      KB, b1, opw16, opb, FB, b2, NPIX, CH, CH);
  // 11. x3 = x2 + cpe2(x2); y4 = LN2(x3)   [fused]
  k_cpe_ln<bf16><<<dim3(NPIX / 16), dim3(192), 0, stream>>>(b2, cpe2w, cpe2b, n2w, n2b, FA, b0);
  // 12. fused MLP: FA += fc2(gelu(fc1(b0)))   [no hidden round-trip]
  k_mlp<<<dim3(NPIX / 128), dim3(256), 0, stream>>>(b0, f1w16, f1b, f2w16, f2b, FA);
  // 13. final transpose NHWC fp32 -> NCHW fp32
  k_transpose_out<<<dim3(6, 128, BQ), tb, 0, stream>>>(FA, out);
}

// Round 11
// 591.664 us; speedup vs baseline: 1.0633x; 1.0633x over previous
//
#include <hip/hip_runtime.h>
#include <hip/hip_bf16.h>

#define BQ 16
#define CH 192
#define HH 64
#define WW 64
#define HWSZ 4096
#define NPIX 65536
#define NHEADS 6
#define HDIM 32
#define NPAIR 96
#define KMAXR 48
#define HID 768

typedef __hip_bfloat16 bf16;
typedef __attribute__((ext_vector_type(8))) short short8;
typedef __attribute__((ext_vector_type(4))) float floatx4;

static __device__ __forceinline__ float b2f(bf16 v) { return __bfloat162float(v); }
static __device__ __forceinline__ bf16 f2b(float v) { return __float2bfloat16(v); }

static __device__ __forceinline__ float4 ld4(const float* p) { return *(const float4*)p; }
static __device__ __forceinline__ float4 ld4(const bf16* p) {
  uint2 u = *(const uint2*)p;
  return make_float4(__uint_as_float(u.x << 16), __uint_as_float(u.x & 0xffff0000u),
                     __uint_as_float(u.y << 16), __uint_as_float(u.y & 0xffff0000u));
}

template <int ACT>
static __device__ __forceinline__ float actf(float v) {
  if (ACT == 1) return v / (1.f + expf(-v));                               // silu
  if (ACT == 2) return (v > 0.f) ? v + 1.f : expf(v);                      // elu+1
  if (ACT == 3) return 0.5f * v * (1.f + erff(v * 0.70710678118654752f));  // gelu
  return v;
}
static __device__ __forceinline__ void stv(float* p, float v) { *p = v; }
static __device__ __forceinline__ void stv(bf16* p, float v) { *p = __float2bfloat16(v); }

// ---------------- transpose NCHW -> NHWC (fp32) ----------------
__global__ __launch_bounds__(256) void k_transpose_in(const float* __restrict__ in,
                                                      float* __restrict__ out) {
  __shared__ float tile[32][33];
  int c0 = blockIdx.x * 32, hw0 = blockIdx.y * 32, b = blockIdx.z;
  int tx = threadIdx.x, ty = threadIdx.y;
  const float* src = in + (size_t)b * CH * HWSZ;
  #pragma unroll
  for (int j = 0; j < 32; j += 8)
    tile[ty + j][tx] = src[(size_t)(c0 + ty + j) * HWSZ + hw0 + tx];
  __syncthreads();
  float* dst = out + (size_t)b * HWSZ * CH;
  #pragma unroll
  for (int j = 0; j < 32; j += 8)
    dst[(size_t)(hw0 + ty + j) * CH + c0 + tx] = tile[tx][ty + j];
}

// ---------------- transpose NHWC -> NCHW (fp32) ----------------
__global__ __launch_bounds__(256) void k_transpose_out(const float* __restrict__ in,
                                                       float* __restrict__ out) {
  __shared__ float tile[32][33];
  int c0 = blockIdx.x * 32, hw0 = blockIdx.y * 32, b = blockIdx.z;
  int tx = threadIdx.x, ty = threadIdx.y;
  const float* src = in + (size_t)b * HWSZ * CH;
  #pragma unroll
  for (int j = 0; j < 32; j += 8)
    tile[ty + j][tx] = src[(size_t)(hw0 + ty + j) * CH + c0 + tx];
  __syncthreads();
  float* dst = out + (size_t)b * CH * HWSZ;
  #pragma unroll
  for (int j = 0; j < 32; j += 8)
    dst[(size_t)(c0 + ty + j) * HWSZ + hw0 + tx] = tile[tx][ty + j];
}

// ---------------- RoPE tables, layout [pair][hw] ----------------
__global__ __launch_bounds__(256) void k_rope(float* __restrict__ cosT, float* __restrict__ sinT) {
  int i = blockIdx.x * 256 + threadIdx.x;
  if (i >= NPAIR * HWSZ) return;
  int hw = i & (HWSZ - 1);
  int p = i >> 12;
  int h = hw >> 6, w = hw & 63;
  int j = (p < KMAXR) ? p : p - KMAXR;
  float theta = powf(10000.f, -(float)j / (float)KMAXR);
  float pos = (p < KMAXR) ? (float)h : (float)w;
  float ang = pos * theta;
  cosT[i] = cosf(ang);
  sinT[i] = sinf(ang);
}

// ---------------- one-shot fp32 -> bf16 weight conversion ----------------
// regions (element offsets): ap 0, ip 36864, qk 73728, op 147456, f1 184320, f2 331776
#define WTOT 479232
__global__ __launch_bounds__(256) void k_wcvt(const float* __restrict__ ap,
                                              const float* __restrict__ ip,
                                              const float* __restrict__ qk,
                                              const float* __restrict__ op,
                                              const float* __restrict__ f1,
                                              const float* __restrict__ f2,
                                              bf16* __restrict__ o) {
  int i = (blockIdx.x * 256 + threadIdx.x) * 4;
  if (i >= WTOT) return;
  const float* src;
  int off;
  if (i < 36864)       { src = ap; off = 0; }
  else if (i < 73728)  { src = ip; off = 36864; }
  else if (i < 147456) { src = qk; off = 73728; }
  else if (i < 184320) { src = op; off = 147456; }
  else if (i < 331776) { src = f1; off = 184320; }
  else                 { src = f2; off = 331776; }
  float4 v = ld4(src + (i - off));
  __align__(8) bf16 t4[4] = {f2b(v.x), f2b(v.y), f2b(v.z), f2b(v.w)};
  *(uint2*)&o[i] = *(uint2*)t4;
}

// ---------------- fused dwconv(residual) + LayerNorm (strip) ----------------
template <typename TI>
__global__ __launch_bounds__(192) void k_cpe_ln(const TI* __restrict__ in,
                                                const float* __restrict__ w,
                                                const float* __restrict__ bias,
                                                const float* __restrict__ g,
                                                const float* __restrict__ bt,
                                                float* __restrict__ x1o,
                                                bf16* __restrict__ yo) {
  __shared__ float grs[12][4], grq[12][4];
  int t = threadIdx.x;
  int cg = t % 48, st = t / 48;
  int c0 = cg * 4;
  int gpix = blockIdx.x * 16 + st * 4;  // first pixel of this strip (incl. batch)
  int hw = gpix & (HWSZ - 1);
  int h = hw >> 6, wx = hw & 63;        // strip covers cols wx..wx+3 of row h
  float4 w4[9];
  #pragma unroll
  for (int i = 0; i < 9; i++) w4[i] = ld4(w + c0 * 9 + i * 4);
  const float* wf = (const float*)w4;
  float4 bi = ld4(bias + c0);
  float4 acc[4];
  #pragma unroll
  for (int i = 0; i < 4; i++) acc[i] = bi;
  const TI* base = in + (size_t)gpix * CH + c0;
  #pragma unroll
  for (int dh = -1; dh <= 1; dh++) {
    bool rv = ((unsigned)(h + dh) < HH);
    float4 tap[6];
    #pragma unroll
    for (int c = 0; c < 6; c++) {
      int col = wx - 1 + c;
      bool v = rv && ((unsigned)col < WW);
      tap[c] = v ? ld4(base + (dh * WW + (c - 1)) * CH) : make_float4(0, 0, 0, 0);
    }
    #pragma unroll
    for (int i = 0; i < 4; i++) {
      #pragma unroll
      for (int dw = 0; dw < 3; dw++) {
        const int tp = (dh + 1) * 3 + dw;
        float4 tv = tap[i + dw];
        acc[i].x += tv.x * wf[0 * 9 + tp];
        acc[i].y += tv.y * wf[1 * 9 + tp];
        acc[i].z += tv.z * wf[2 * 9 + tp];
        acc[i].w += tv.w * wf[3 * 9 + tp];
      }
      if (dh == 0) {  // residual: x + conv(x)
        acc[i].x += tap[i + 1].x;
        acc[i].y += tap[i + 1].y;
        acc[i].z += tap[i + 1].z;
        acc[i].w += tap[i + 1].w;
      }
    }
  }
  float s4[4], q4[4];
  #pragma unroll
  for (int i = 0; i < 4; i++) {
    *(float4*)&x1o[(size_t)(gpix + i) * CH + c0] = acc[i];
    s4[i] = acc[i].x + acc[i].y + acc[i].z + acc[i].w;
    q4[i] = acc[i].x * acc[i].x + acc[i].y * acc[i].y + acc[i].z * acc[i].z +
            acc[i].w * acc[i].w;
  }
  #pragma unroll
  for (int m = 1; m <= 8; m <<= 1) {
    #pragma unroll
    for (int i = 0; i < 4; i++) {
      s4[i] += __shfl_xor(s4[i], m, 64);
      q4[i] += __shfl_xor(q4[i], m, 64);
    }
  }
  if ((t & 15) == 0) {
    #pragma unroll
    for (int i = 0; i < 4; i++) { grs[t >> 4][i] = s4[i]; grq[t >> 4][i] = q4[i]; }
  }
  __syncthreads();
  int s3 = st * 3;
  float4 gg = ld4(g + c0);
  float4 bb = ld4(bt + c0);
  #pragma unroll
  for (int i = 0; i < 4; i++) {
    float S = grs[s3][i] + grs[s3 + 1][i] + grs[s3 + 2][i];
    float SS = grq[s3][i] + grq[s3 + 1][i] + grq[s3 + 2][i];
    float mu = S * (1.f / CH);
    float inv = rsqrtf(SS * (1.f / CH) - mu * mu + 1e-5f);
    __align__(8) bf16 tmp[4] = {f2b((acc[i].x - mu) * inv * gg.x + bb.x),
                                f2b((acc[i].y - mu) * inv * gg.y + bb.y),
                                f2b((acc[i].z - mu) * inv * gg.z + bb.z),
                                f2b((acc[i].w - mu) * inv * gg.w + bb.w)};
    *(uint2*)&yo[(size_t)(gpix + i) * CH + c0] = *(uint2*)tmp;
  }
}

// ---------------- strip dwconv, bf16 in/out, 4ch x 4 pixels per thread ----------------
// MODE 1: out = silu(conv+bias)   MODE 2: out += conv+bias
template <int MODE>
__global__ __launch_bounds__(192) void k_dwconv_strip(const bf16* __restrict__ in,
                                                      const float* __restrict__ w,
                                                      const float* __restrict__ bias,
                                                      bf16* __restrict__ out) {
  int t = threadIdx.x;
  int cg = t % 48, st = t / 48;
  int c0 = cg * 4;
  int gpix = blockIdx.x * 16 + st * 4;
  int hw = gpix & (HWSZ - 1);
  int h = hw >> 6, wx = hw & 63;
  float4 w4[9];
  #pragma unroll
  for (int i = 0; i < 9; i++) w4[i] = ld4(w + c0 * 9 + i * 4);
  const float* wf = (const float*)w4;
  float4 bi = ld4(bias + c0);
  float4 acc[4];
  #pragma unroll
  for (int i = 0; i < 4; i++) acc[i] = bi;
  const bf16* base = in + (size_t)gpix * CH + c0;
  #pragma unroll
  for (int dh = -1; dh <= 1; dh++) {
    bool rv = ((unsigned)(h + dh) < HH);
    float4 tap[6];
    #pragma unroll
    for (int c = 0; c < 6; c++) {
      int col = wx - 1 + c;
      bool v = rv && ((unsigned)col < WW);
      tap[c] = v ? ld4(base + (dh * WW + (c - 1)) * CH) : make_float4(0, 0, 0, 0);
    }
    #pragma unroll
    for (int i = 0; i < 4; i++) {
      #pragma unroll
      for (int dw = 0; dw < 3; dw++) {
        const int tp = (dh + 1) * 3 + dw;
        float4 tv = tap[i + dw];
        acc[i].x += tv.x * wf[0 * 9 + tp];
        acc[i].y += tv.y * wf[1 * 9 + tp];
        acc[i].z += tv.z * wf[2 * 9 + tp];
        acc[i].w += tv.w * wf[3 * 9 + tp];
      }
    }
  }
  #pragma unroll
  for (int i = 0; i < 4; i++) {
    bf16* op = out + (size_t)(gpix + i) * CH + c0;
    float a0 = acc[i].x, a1 = acc[i].y, a2 = acc[i].z, a3 = acc[i].w;
    if (MODE == 1) {
      a0 = a0 / (1.f + expf(-a0));
      a1 = a1 / (1.f + expf(-a1));
      a2 = a2 / (1.f + expf(-a2));
      a3 = a3 / (1.f + expf(-a3));
    } else {
      float4 cur = ld4(op);
      a0 += cur.x; a1 += cur.y; a2 += cur.z; a3 += cur.w;
    }
    __align__(8) bf16 tmp[4] = {f2b(a0), f2b(a1), f2b(a2), f2b(a3)};
    *(uint2*)op = *(uint2*)tmp;
  }
}

// ---------------- MFMA bf16 GEMM: tile 128x64, BK=64, 27.6KB LDS ----------------
// BK=64 -> 4 blocks/CU resident; proven round-7 epilogue (scattered stores).
template <int ACT, int MULA, int RES, typename TO>
__global__ __launch_bounds__(256) void k_gemm(const bf16* __restrict__ A,
                                              const bf16* __restrict__ A2,
                                              const bf16* __restrict__ Wt,
                                              const float* __restrict__ bias,
                                              const float* __restrict__ Rsd,
                                              TO* __restrict__ Cout,
                                              int M, int N, int K) {
  __shared__ bf16 As[128][72];
  __shared__ bf16 Bs[64][72];
  int t = threadIdx.x;
  int wave = t >> 6, lane = t & 63;
  int quad = lane >> 4, l16 = lane & 15;
  int m0 = blockIdx.x * 128, n0 = blockIdx.y * 64;
  floatx4 acc[2][4] = {};
  for (int kc = 0; kc < K; kc += 64) {
    #pragma unroll
    for (int i = 0; i < 4; i++) {
      int idx = t + i * 256;
      int m = idx >> 3, ck = (idx & 7) * 8;
      const bf16* pa = &A[(size_t)(m0 + m) * K + kc + ck];
      if (!MULA) {
        *(short8*)&As[m][ck] = *(const short8*)pa;
      } else {
        const bf16* pb = &A2[(size_t)(m0 + m) * K + kc + ck];
        __align__(16) bf16 tmp[8];
        #pragma unroll
        for (int j = 0; j < 8; j++) tmp[j] = f2b(b2f(pa[j]) * b2f(pb[j]));
        *(short8*)&As[m][ck] = *(const short8*)tmp;
      }
    }
    #pragma unroll
    for (int i = 0; i < 2; i++) {
      int idx = t + i * 256;
      int n = idx >> 3, ck = (idx & 7) * 8;
      *(short8*)&Bs[n][ck] = *(const short8*)&Wt[(size_t)(n0 + n) * K + kc + ck];
    }
    __syncthreads();
    #pragma unroll
    for (int ks = 0; ks < 2; ks++) {
      short8 af[2], bfr[4];
      #pragma unroll
      for (int i = 0; i < 2; i++)
        af[i] = *(const short8*)&As[wave * 32 + i * 16 + l16][ks * 32 + quad * 8];
      #pragma unroll
      for (int j = 0; j < 4; j++)
        bfr[j] = *(const short8*)&Bs[j * 16 + l16][ks * 32 + quad * 8];
      #pragma unroll
      for (int i = 0; i < 2; i++)
        #pragma unroll
        for (int j = 0; j < 4; j++)
          acc[i][j] = __builtin_amdgcn_mfma_f32_16x16x32_bf16(af[i], bfr[j], acc[i][j], 0, 0, 0);
    }
    __syncthreads();
  }
  #pragma unroll
  for (int i = 0; i < 2; i++) {
    #pragma unroll
    for (int j = 0; j < 4; j++) {
      int n = n0 + j * 16 + l16;
      float bn = bias[n];
      #pragma unroll
      for (int r = 0; r < 4; r++) {
        int m = m0 + wave * 32 + i * 16 + quad * 4 + r;
        float v = actf<ACT>(acc[i][j][r] + bn);
        if (RES) v += Rsd[(size_t)m * N + n];
        stv(&Cout[(size_t)m * N + n], v);
      }
    }
  }
}

// dual-output GEMM (K=192, BK=64): N=384 as two 192 halves; optional fused col-mean of half B.
template <int ACTA, int ACTB, int KMEAN>
__global__ __launch_bounds__(256) void k_gemm_dual(const bf16* __restrict__ A,
                                                   const bf16* __restrict__ WtA,
                                                   const float* __restrict__ biasA,
                                                   const bf16* __restrict__ WtB,
                                                   const float* __restrict__ biasB,
                                                   bf16* __restrict__ OutA,
                                                   bf16* __restrict__ OutB,
                                                   float* __restrict__ KM,
                                                   int K) {
  __shared__ bf16 As[128][72];
  __shared__ bf16 Bs[64][72];
  __shared__ float colsum[64];
  int t = threadIdx.x;
  int wave = t >> 6, lane = t & 63;
  int quad = lane >> 4, l16 = lane & 15;
  int m0 = blockIdx.x * 128, n0 = blockIdx.y * 64;
  int half = n0 >= 192;
  int n0l = half ? n0 - 192 : n0;
  const bf16* Wt = half ? WtB : WtA;
  const float* bias = half ? biasB : biasA;
  bf16* Out = half ? OutB : OutA;
  if (KMEAN && half && t < 64) colsum[t] = 0.f;
  floatx4 acc[2][4] = {};
  for (int kc = 0; kc < CH; kc += 64) {
    #pragma unroll
    for (int i = 0; i < 4; i++) {
      int idx = t + i * 256;
      int m = idx >> 3, ck = (idx & 7) * 8;
      *(short8*)&As[m][ck] = *(const short8*)&A[(size_t)(m0 + m) * CH + kc + ck];
    }
    #pragma unroll
    for (int i = 0; i < 2; i++) {
      int idx = t + i * 256;
      int n = idx >> 3, ck = (idx & 7) * 8;
      *(short8*)&Bs[n][ck] = *(const short8*)&Wt[(size_t)(n0l + n) * CH + kc + ck];
    }
    __syncthreads();
    #pragma unroll
    for (int ks = 0; ks < 2; ks++) {
      short8 af[2], bfr[4];
      #pragma unroll
      for (int i = 0; i < 2; i++)
        af[i] = *(const short8*)&As[wave * 32 + i * 16 + l16][ks * 32 + quad * 8];
      #pragma unroll
      for (int j = 0; j < 4; j++)
        bfr[j] = *(const short8*)&Bs[j * 16 + l16][ks * 32 + quad * 8];
      #pragma unroll
      for (int i = 0; i < 2; i++)
        #pragma unroll
        for (int j = 0; j < 4; j++)
          acc[i][j] = __builtin_amdgcn_mfma_f32_16x16x32_bf16(af[i], bfr[j], acc[i][j], 0, 0, 0);
    }
    __syncthreads();
  }
  #pragma unroll
  for (int j = 0; j < 4; j++) {
    int nl = n0l + j * 16 + l16;
    float bn = bias[nl];
    float csum = 0.f;
    #pragma unroll
    for (int i = 0; i < 2; i++) {
      #pragma unroll
      for (int r = 0; r < 4; r++) {
        int m = m0 + wave * 32 + i * 16 + quad * 4 + r;
        float v = half ? actf<ACTB>(acc[i][j][r] + bn) : actf<ACTA>(acc[i][j][r] + bn);
        if (KMEAN && half) csum += v;
        Out[(size_t)m * CH + nl] = f2b(v);
      }
    }
    if (KMEAN && half) atomicAdd(&colsum[j * 16 + l16], csum);
  }
  if (KMEAN && half) {
    __syncthreads();
    if (t < 64) {
      int b = m0 >> 12;
      atomicAdd(&KM[b * CH + n0l + t], colsum[t] * (1.f / 4096.f));
    }
  }
}

// ---------------- fused MLP v2: out += fc2(gelu(fc1(y))), M-tile = 64 ----------------
// v1 failed at 190us: acc regs (96+32) + VGPRs > 256/wave -> 1 wave/SIMD, serial.
// v2: 64 pixels/block, wave owns 16 rows -> acc2=48, acc1=16 regs; LDS 48KB -> 3 blocks/CU.
// fc1/fc2 k-chunk order identical to the unfused BK=64 path (same numerics).
__global__ __launch_bounds__(256) void k_mlp(const bf16* __restrict__ Y,
                                             const bf16* __restrict__ W1,
                                             const float* __restrict__ B1,
                                             const bf16* __restrict__ W2,
                                             const float* __restrict__ B2,
                                             float* __restrict__ XR) {
  __shared__ bf16 As[64][72];
  __shared__ bf16 Bs[192][72];
  __shared__ bf16 Hs[64][88];   // 88: 16B-aligned rows; quad write-offset 16dw -> 4-way max
  int t = threadIdx.x;
  int wave = t >> 6, lane = t & 63;
  int quad = lane >> 4, l16 = lane & 15;
  int m0 = blockIdx.x * 64;
  floatx4 acc2[12] = {};
  for (int hc = 0; hc < 12; hc++) {
    int h0 = hc * 64;
    floatx4 acc1[4] = {};
    for (int ks3 = 0; ks3 < 3; ks3++) {
      int kc = ks3 * 64;
      #pragma unroll
      for (int i = 0; i < 2; i++) {
        int idx = t + i * 256;
        int m = idx >> 3, ck = (idx & 7) * 8;
        *(short8*)&As[m][ck] = *(const short8*)&Y[(size_t)(m0 + m) * CH + kc + ck];
      }
      #pragma unroll
      for (int i = 0; i < 2; i++) {
        int idx = t + i * 256;
        int n = idx >> 3, ck = (idx & 7) * 8;
        *(short8*)&Bs[n][ck] = *(const short8*)&W1[(size_t)(h0 + n) * CH + kc + ck];
      }
      __syncthreads();
      #pragma unroll
      for (int ks = 0; ks < 2; ks++) {
        short8 af = *(const short8*)&As[wave * 16 + l16][ks * 32 + quad * 8];
        #pragma unroll
        for (int j = 0; j < 4; j++) {
          short8 bfr = *(const short8*)&Bs[j * 16 + l16][ks * 32 + quad * 8];
          acc1[j] = __builtin_amdgcn_mfma_f32_16x16x32_bf16(af, bfr, acc1[j], 0, 0, 0);
        }
      }
      __syncthreads();
    }
    // gelu(acc1 + b1) -> Hs (bf16); C/D layout col=lane&15, row=quad*4+r
    #pragma unroll
    for (int j = 0; j < 4; j++) {
      int col = j * 16 + l16;
      float bn = B1[h0 + col];
      #pragma unroll
      for (int r = 0; r < 4; r++) {
        int row = wave * 16 + quad * 4 + r;
        float v = acc1[j][r] + bn;
        Hs[row][col] = f2b(0.5f * v * (1.f + erff(v * 0.70710678118654752f)));
      }
    }
    // stage W2 chunk: Bs[n out=0..191][ck h]
    #pragma unroll
    for (int i = 0; i < 6; i++) {
      int idx = t + i * 256;
      int n = idx >> 3, ck = (idx & 7) * 8;
      *(short8*)&Bs[n][ck] = *(const short8*)&W2[(size_t)n * HID + h0 + ck];
    }
    __syncthreads();
    #pragma unroll
    for (int ks = 0; ks < 2; ks++) {
      short8 af = *(const short8*)&Hs[wave * 16 + l16][ks * 32 + quad * 8];
      #pragma unroll
      for (int j = 0; j < 12; j++) {
        short8 bfr = *(const short8*)&Bs[j * 16 + l16][ks * 32 + quad * 8];
        acc2[j] = __builtin_amdgcn_mfma_f32_16x16x32_bf16(af, bfr, acc2[j], 0, 0, 0);
      }
    }
    __syncthreads();  // fc2 reads done before next chunk overwrites As/Bs/Hs
  }
  // epilogue: out = acc2 + b2 + residual (XR fp32, read-modify-write)
  #pragma unroll
  for (int j = 0; j < 12; j++) {
    int n = j * 16 + l16;
    float bn = B2[n];
    #pragma unroll
    for (int r = 0; r < 4; r++) {
      int m = m0 + wave * 16 + quad * 4 + r;
      float* p = &XR[(size_t)m * CH + n];
      *p = acc2[j][r] + bn + *p;
    }
  }
}

// ---------------- kv via MFMA: kv[d][e] = sum_n K_rope[n][d] * V[n][e] ----------------
__global__ __launch_bounds__(256) void k_kv(const bf16* __restrict__ k,
                                            const bf16* __restrict__ v,
                                            const float* __restrict__ cosT,
                                            const float* __restrict__ sinT,
                                            float* __restrict__ kv) {
  int bh = blockIdx.x;
  int b = bh / NHEADS, hd = bh % NHEADS;
  int chunk0 = blockIdx.y * 512;
  __shared__ __align__(16) bf16 kst[32][280];
  __shared__ __align__(16) bf16 vst[32][280];
  int t = threadIdx.x;
  int wave = t >> 6, lane = t & 63;
  int quad = lane >> 4, l16 = lane & 15;
  int dh = wave >> 1, eh = wave & 1;
  floatx4 acc = {};
  for (int sub = 0; sub < 2; sub++) {
    int n0 = chunk0 + sub * 256;
    #pragma unroll
    for (int it = 0; it < 4; it++) {
      int idx = t + it * 256;            // 0..1023 = 256 rows x 4 c-groups
      int row = idx >> 2, c0 = (idx & 3) * 8;
      int n = n0 + row;
      size_t gi = ((size_t)(b * HWSZ + n)) * CH + hd * HDIM + c0;
      short8 vv = *(const short8*)&v[gi];
      #pragma unroll
      for (int j = 0; j < 8; j++) vst[c0 + j][row] = ((const bf16*)&vv)[j];
      float4 klo = ld4(&k[gi]);
      float4 khi = ld4(&k[gi + 4]);
      int prb = hd * 16 + (c0 >> 1);
      float cs0 = cosT[(size_t)(prb + 0) * HWSZ + n];
      float sn0 = sinT[(size_t)(prb + 0) * HWSZ + n];
      float cs1 = cosT[(size_t)(prb + 1) * HWSZ + n];
      float sn1 = sinT[(size_t)(prb + 1) * HWSZ + n];
      float cs2 = cosT[(size_t)(prb + 2) * HWSZ + n];
      float sn2 = sinT[(size_t)(prb + 2) * HWSZ + n];
      float cs3 = cosT[(size_t)(prb + 3) * HWSZ + n];
      float sn3 = sinT[(size_t)(prb + 3) * HWSZ + n];
      kst[c0 + 0][row] = f2b(klo.x * cs0 - klo.y * sn0);
      kst[c0 + 1][row] = f2b(klo.x * sn0 + klo.y * cs0);
      kst[c0 + 2][row] = f2b(klo.z * cs1 - klo.w * sn1);
      kst[c0 + 3][row] = f2b(klo.z * sn1 + klo.w * cs1);
      kst[c0 + 4][row] = f2b(khi.x * cs2 - khi.y * sn2);
      kst[c0 + 5][row] = f2b(khi.x * sn2 + khi.y * cs2);
      kst[c0 + 6][row] = f2b(khi.z * cs3 - khi.w * sn3);
      kst[c0 + 7][row] = f2b(khi.z * sn3 + khi.w * cs3);
    }
    __syncthreads();
    #pragma unroll
    for (int ks = 0; ks < 8; ks++) {
      short8 af = *(const short8*)&kst[dh * 16 + l16][ks * 32 + quad * 8];
      short8 bfr = *(const short8*)&vst[eh * 16 + l16][ks * 32 + quad * 8];
      acc = __builtin_amdgcn_mfma_f32_16x16x32_bf16(af, bfr, acc, 0, 0, 0);
    }
    __syncthreads();
  }
  // C/D layout: col = lane&15, row = quad*4 + r  (m89-verified)
  int d = dh * 16 + quad * 4;
  int e = eh * 16 + l16;
  float* dst = kv + (size_t)bh * (HDIM * HDIM) + (size_t)d * HDIM + e;
  const float sc = 1.f / 4096.f;
  #pragma unroll
  for (int r = 0; r < 4; r++) atomicAdd(dst + r * HDIM, acc[r] * sc);
}

// ---------------- attn via MFMA: out = (rope(q) @ kv) * zi ----------------
__global__ __launch_bounds__(256) void k_attn(const bf16* __restrict__ q,
                                              const float* __restrict__ kv,
                                              const float* __restrict__ kmean,
                                              const float* __restrict__ cosT,
                                              const float* __restrict__ sinT,
                                              bf16* __restrict__ attn) {
  int hd = blockIdx.y, b = blockIdx.z;
  int t = threadIdx.x;
  int hw = blockIdx.x * 256 + t;
  int bh = b * NHEADS + hd;
  __shared__ __align__(16) bf16 As[256][40];
  __shared__ __align__(16) bf16 Bs[32][40];
  int wave = t >> 6, lane = t & 63;
  int quad = lane >> 4, l16 = lane & 15;
  // stage kv^T -> Bs[e][d] (bf16)
  {
    int e = t >> 3, d0 = (t & 7) * 4;
    const float* kvp = kv + (size_t)bh * 1024;
    __align__(8) bf16 tmp[4] = {f2b(kvp[(d0 + 0) * 32 + e]), f2b(kvp[(d0 + 1) * 32 + e]),
                                f2b(kvp[(d0 + 2) * 32 + e]), f2b(kvp[(d0 + 3) * 32 + e])};
    *(uint2*)&Bs[e][d0] = *(uint2*)tmp;
  }
  // per-pixel: z (pre-rope) and rope(q) -> As[t][:]
  int pix = b * HWSZ + hw;
  const bf16* qp = q + (size_t)pix * CH + hd * HDIM;
  float qv[32];
  #pragma unroll
  for (int i = 0; i < 32; i++) qv[i] = b2f(qp[i]);
  const float* km = kmean + b * CH + hd * HDIM;
  float z = 1e-6f;
  #pragma unroll
  for (int d = 0; d < 32; d++) z += qv[d] * km[d];
  float zi = 1.f / z;
  __align__(16) bf16 ar[32];
  #pragma unroll
  for (int p = 0; p < 16; p++) {
    float cs = cosT[(size_t)(hd * 16 + p) * HWSZ + hw];
    float sn = sinT[(size_t)(hd * 16 + p) * HWSZ + hw];
    float re = qv[2 * p], im = qv[2 * p + 1];
    ar[2 * p] = f2b(re * cs - im * sn);
    ar[2 * p + 1] = f2b(re * sn + im * cs);
  }
  #pragma unroll
  for (int i = 0; i < 4; i++) *(short8*)&As[t][i * 8] = *(const short8*)&ar[i * 8];
  __syncthreads();
  // MFMA: wave w owns pixels [w*64, w*64+64): 4 m-tiles x 2 n-tiles
  short8 af[4], bfr[2];
  #pragma unroll
  for (int nt = 0; nt < 2; nt++) bfr[nt] = *(const short8*)&Bs[nt * 16 + l16][quad * 8];
  #pragma unroll
  for (int mt = 0; mt < 4; mt++)
    af[mt] = *(const short8*)&As[wave * 64 + mt * 16 + l16][quad * 8];
  floatx4 acc[4][2] = {};
  #pragma unroll
  for (int mt = 0; mt < 4; mt++)
    #pragma unroll
    for (int nt = 0; nt < 2; nt++)
      acc[mt][nt] = __builtin_amdgcn_mfma_f32_16x16x32_bf16(af[mt], bfr[nt], acc[mt][nt], 0, 0, 0);
  __syncthreads();
  // C restage into As: row = pixel (wave-local), col = e
  #pragma unroll
  for (int mt = 0; mt < 4; mt++)
    #pragma unroll
    for (int nt = 0; nt < 2; nt++) {
      int row = wave * 64 + mt * 16 + quad * 4;
      int col = nt * 16 + l16;
      #pragma unroll
      for (int r = 0; r < 4; r++) As[row + r][col] = f2b(acc[mt][nt][r]);
    }
  __syncthreads();
  // each thread: read its own pixel row, scale by in-register zi, coalesced store
  bf16* op = attn + (size_t)pix * CH + hd * HDIM;
  #pragma unroll
  for (int i = 0; i < 4; i++) {
    short8 vv = *(const short8*)&As[t][i * 8];
    __align__(16) bf16 tmp[8];
    #pragma unroll
    for (int j = 0; j < 8; j++) tmp[j] = f2b(b2f(((const bf16*)&vv)[j]) * zi);
    *(short8*)&op[i * 8] = *(const short8*)tmp;
  }
}

extern "C" void kernel_launch(void* const* d_in, const int* in_sizes, int n_in,
                              void* d_out, int out_size, void* d_ws, size_t ws_size,
                              hipStream_t stream) {
  const float* x = (const float*)d_in[0];
  const float* cpe1w = (const float*)d_in[1];
  const float* cpe1b = (const float*)d_in[2];
  const float* n1w = (const float*)d_in[3];
  const float* n1b = (const float*)d_in[4];
  const float* apw = (const float*)d_in[5];
  const float* apb = (const float*)d_in[6];
  const float* ipw = (const float*)d_in[7];
  const float* ipb = (const float*)d_in[8];
  const float* dwcw = (const float*)d_in[9];
  const float* dwcb = (const float*)d_in[10];
  const float* qkw = (const float*)d_in[11];
  const float* qkb = (const float*)d_in[12];
  const float* lepw = (const float*)d_in[13];
  const float* lepb = (const float*)d_in[14];
  const float* opw = (const float*)d_in[15];
  const float* opb = (const float*)d_in[16];
  const float* cpe2w = (const float*)d_in[17];
  const float* cpe2b = (const float*)d_in[18];
  const float* n2w = (const float*)d_in[19];
  const float* n2b = (const float*)d_in[20];
  const float* f1w = (const float*)d_in[21];
  const float* f1b = (const float*)d_in[22];
  const float* f2w = (const float*)d_in[23];
  const float* f2b = (const float*)d_in[24];
  float* out = (float*)d_out;

  float* ws = (float*)d_ws;
  const size_t S = (size_t)NPIX * CH;
  float* FA = ws;                       // fp32: x NHWC -> (bf16 k/attn scratch) -> x3 -> final
  float* FB = ws + S;                   // fp32: x1
  bf16* barena = (bf16*)(ws + 2 * S);
  bf16* b0 = barena;                    // y -> t/v -> y4
  bf16* b1 = barena + S;                // act_res
  bf16* b2 = barena + 2 * S;            // y2 -> q -> x2
  bf16* KB = (bf16*)FA;                 // k, then attn (FA dead between cpe1 and cpe2)
  float* COS = ws + 2 * S + 3 * S / 2;
  float* SIN = COS + (size_t)NPAIR * HWSZ;
  float* KV = SIN + (size_t)NPAIR * HWSZ;
  float* KM = KV + BQ * NHEADS * HDIM * HDIM;
  bf16* WB = (bf16*)(KM + BQ * CH);     // bf16 weight arena (479232 elems)
  bf16* apw16 = WB;
  bf16* ipw16 = WB + 36864;
  bf16* qkw16 = WB + 73728;             // [384][192]; halves at +0 and +36864
  bf16* opw16 = WB + 147456;
  bf16* f1w16 = WB + 184320;
  bf16* f2w16 = WB + 331776;

  dim3 tb(32, 8);
  // 0. weights -> bf16 once
  k_wcvt<<<dim3((WTOT / 4 + 255) / 256), dim3(256), 0, stream>>>(
      apw, ipw, qkw, opw, f1w, f2w, WB);
  // 1. transpose input NCHW -> NHWC fp32
  k_transpose_in<<<dim3(6, 128, BQ), tb, 0, stream>>>(x, FA);
  // 2. rope tables [pair][hw]
  k_rope<<<dim3(NPAIR * HWSZ / 256), dim3(256), 0, stream>>>(COS, SIN);
  // 3. x1 = x + cpe1(x); y = LN1(x1)   [fused]
  k_cpe_ln<float><<<dim3(NPIX / 16), dim3(192), 0, stream>>>(FA, cpe1w, cpe1b, n1w, n1b, FB, b0);
  // 4. act_res = silu(act_proj(y)); y2 = in_proj(y)
  k_gemm_dual<1, 0, 0><<<dim3(NPIX / 128, 6), dim3(256), 0, stream>>>(
      b0, apw16, apb, ipw16, ipb, b1, b2, nullptr, CH);
  // 5. t = v = silu(dwc(y2))
  k_dwconv_strip<1><<<dim3(NPIX / 16), dim3(192), 0, stream>>>(b2, dwcw, dwcb, b0);
  // 6. q,k = elu(t @ qk_w^T + qk_b)+1 ; kmean fused into k epilogue
  hipMemsetAsync(KM, 0, (size_t)BQ * CH * sizeof(float), stream);
  k_gemm_dual<2, 2, 1><<<dim3(NPIX / 128, 6), dim3(256), 0, stream>>>(
      b0, qkw16, qkb, qkw16 + CH * CH, qkb + CH, b2, KB, KM, CH);
  // 7. kv accumulate (fused rope, MFMA, 512 rows/block)
  hipMemsetAsync(KV, 0, (size_t)BQ * NHEADS * HDIM * HDIM * sizeof(float), stream);
  k_kv<<<dim3(BQ * NHEADS, 8), dim3(256), 0, stream>>>(KB, b0, COS, SIN, KV);
  // 8. attn = (q_rope @ kv) * z  -> KB (k dead)
  k_attn<<<dim3(HWSZ / 256, NHEADS, BQ), dim3(256), 0, stream>>>(b2, KV, KM, COS, SIN, KB);
  // 9. attn += lepe(v)
  k_dwconv_strip<2><<<dim3(NPIX / 16), dim3(192), 0, stream>>>(b0, lepw, lepb, KB);
  // 10. x2 = x1 + out_proj(attn * act_res)  -> b2 (bf16)
  k_gemm<0, 1, 1, bf16><<<dim3(NPIX / 128, 3), dim3(256), 0, stream>>>(
      KB, b1, opw16, opb, FB, b2, NPIX, CH, CH);
  // 11. x3 = x2 + cpe2(x2); y4 = LN2(x3)   [fused]
  k_cpe_ln<bf16><<<dim3(NPIX / 16), dim3(192), 0, stream>>>(b2, cpe2w, cpe2b, n2w, n2b, FA, b0);
  // 12. fused MLP v2 (M=64 tiles): FA += fc2(gelu(fc1(b0)))
  k_mlp<<<dim3(NPIX / 64), dim3(256), 0, stream>>>(b0, f1w16, f1b, f2w16, f2b, FA);
  // 13. final transpose NHWC fp32 -> NCHW fp32
  k_transpose_out<<<dim3(6, 128, BQ), tb, 0, stream>>>(FA, out);
}

// Round 12
// 580.292 us; speedup vs baseline: 1.0841x; 1.0196x over previous
//
#include <hip/hip_runtime.h>
#include <hip/hip_bf16.h>

#define BQ 16
#define CH 192
#define HH 64
#define WW 64
#define HWSZ 4096
#define NPIX 65536
#define NHEADS 6
#define HDIM 32
#define NPAIR 96
#define KMAXR 48
#define HID 768

typedef __hip_bfloat16 bf16;
typedef __attribute__((ext_vector_type(8))) short short8;
typedef __attribute__((ext_vector_type(4))) float floatx4;

static __device__ __forceinline__ float b2f(bf16 v) { return __bfloat162float(v); }
static __device__ __forceinline__ bf16 f2b(float v) { return __float2bfloat16(v); }

static __device__ __forceinline__ float4 ld4(const float* p) { return *(const float4*)p; }
static __device__ __forceinline__ float4 ld4(const bf16* p) {
  uint2 u = *(const uint2*)p;
  return make_float4(__uint_as_float(u.x << 16), __uint_as_float(u.x & 0xffff0000u),
                     __uint_as_float(u.y << 16), __uint_as_float(u.y & 0xffff0000u));
}

template <int ACT>
static __device__ __forceinline__ float actf(float v) {
  if (ACT == 1) return v / (1.f + expf(-v));                               // silu
  if (ACT == 2) return (v > 0.f) ? v + 1.f : expf(v);                      // elu+1
  if (ACT == 3) return 0.5f * v * (1.f + erff(v * 0.70710678118654752f));  // gelu
  return v;
}
static __device__ __forceinline__ void stv(float* p, float v) { *p = v; }
static __device__ __forceinline__ void stv(bf16* p, float v) { *p = __float2bfloat16(v); }

// ---------------- transpose NCHW -> NHWC (fp32) ----------------
__global__ __launch_bounds__(256) void k_transpose_in(const float* __restrict__ in,
                                                      float* __restrict__ out) {
  __shared__ float tile[32][33];
  int c0 = blockIdx.x * 32, hw0 = blockIdx.y * 32, b = blockIdx.z;
  int tx = threadIdx.x, ty = threadIdx.y;
  const float* src = in + (size_t)b * CH * HWSZ;
  #pragma unroll
  for (int j = 0; j < 32; j += 8)
    tile[ty + j][tx] = src[(size_t)(c0 + ty + j) * HWSZ + hw0 + tx];
  __syncthreads();
  float* dst = out + (size_t)b * HWSZ * CH;
  #pragma unroll
  for (int j = 0; j < 32; j += 8)
    dst[(size_t)(hw0 + ty + j) * CH + c0 + tx] = tile[tx][ty + j];
}

// ---------------- transpose NHWC -> NCHW (fp32) ----------------
__global__ __launch_bounds__(256) void k_transpose_out(const float* __restrict__ in,
                                                       float* __restrict__ out) {
  __shared__ float tile[32][33];
  int c0 = blockIdx.x * 32, hw0 = blockIdx.y * 32, b = blockIdx.z;
  int tx = threadIdx.x, ty = threadIdx.y;
  const float* src = in + (size_t)b * HWSZ * CH;
  #pragma unroll
  for (int j = 0; j < 32; j += 8)
    tile[ty + j][tx] = src[(size_t)(hw0 + ty + j) * CH + c0 + tx];
  __syncthreads();
  float* dst = out + (size_t)b * CH * HWSZ;
  #pragma unroll
  for (int j = 0; j < 32; j += 8)
    dst[(size_t)(c0 + ty + j) * HWSZ + hw0 + tx] = tile[tx][ty + j];
}

// ---------------- RoPE tables, layout [pair][hw] ----------------
__global__ __launch_bounds__(256) void k_rope(float* __restrict__ cosT, float* __restrict__ sinT) {
  int i = blockIdx.x * 256 + threadIdx.x;
  if (i >= NPAIR * HWSZ) return;
  int hw = i & (HWSZ - 1);
  int p = i >> 12;
  int h = hw >> 6, w = hw & 63;
  int j = (p < KMAXR) ? p : p - KMAXR;
  float theta = powf(10000.f, -(float)j / (float)KMAXR);
  float pos = (p < KMAXR) ? (float)h : (float)w;
  float ang = pos * theta;
  cosT[i] = cosf(ang);
  sinT[i] = sinf(ang);
}

// ---------------- one-shot fp32 -> bf16 weight conversion ----------------
// regions (element offsets): ap 0, ip 36864, qk 73728, op 147456, f1 184320, f2 331776
#define WTOT 479232
__global__ __launch_bounds__(256) void k_wcvt(const float* __restrict__ ap,
                                              const float* __restrict__ ip,
                                              const float* __restrict__ qk,
                                              const float* __restrict__ op,
                                              const float* __restrict__ f1,
                                              const float* __restrict__ f2,
                                              bf16* __restrict__ o) {
  int i = (blockIdx.x * 256 + threadIdx.x) * 4;
  if (i >= WTOT) return;
  const float* src;
  int off;
  if (i < 36864)       { src = ap; off = 0; }
  else if (i < 73728)  { src = ip; off = 36864; }
  else if (i < 147456) { src = qk; off = 73728; }
  else if (i < 184320) { src = op; off = 147456; }
  else if (i < 331776) { src = f1; off = 184320; }
  else                 { src = f2; off = 331776; }
  float4 v = ld4(src + (i - off));
  __align__(8) bf16 t4[4] = {f2b(v.x), f2b(v.y), f2b(v.z), f2b(v.w)};
  *(uint2*)&o[i] = *(uint2*)t4;
}

// ---------------- fused dwconv(residual) + LayerNorm (strip) ----------------
template <typename TI>
__global__ __launch_bounds__(192) void k_cpe_ln(const TI* __restrict__ in,
                                                const float* __restrict__ w,
                                                const float* __restrict__ bias,
                                                const float* __restrict__ g,
                                                const float* __restrict__ bt,
                                                float* __restrict__ x1o,
                                                bf16* __restrict__ yo) {
  __shared__ float grs[12][4], grq[12][4];
  int t = threadIdx.x;
  int cg = t % 48, st = t / 48;
  int c0 = cg * 4;
  int gpix = blockIdx.x * 16 + st * 4;  // first pixel of this strip (incl. batch)
  int hw = gpix & (HWSZ - 1);
  int h = hw >> 6, wx = hw & 63;        // strip covers cols wx..wx+3 of row h
  float4 w4[9];
  #pragma unroll
  for (int i = 0; i < 9; i++) w4[i] = ld4(w + c0 * 9 + i * 4);
  const float* wf = (const float*)w4;
  float4 bi = ld4(bias + c0);
  float4 acc[4];
  #pragma unroll
  for (int i = 0; i < 4; i++) acc[i] = bi;
  const TI* base = in + (size_t)gpix * CH + c0;
  #pragma unroll
  for (int dh = -1; dh <= 1; dh++) {
    bool rv = ((unsigned)(h + dh) < HH);
    float4 tap[6];
    #pragma unroll
    for (int c = 0; c < 6; c++) {
      int col = wx - 1 + c;
      bool v = rv && ((unsigned)col < WW);
      tap[c] = v ? ld4(base + (dh * WW + (c - 1)) * CH) : make_float4(0, 0, 0, 0);
    }
    #pragma unroll
    for (int i = 0; i < 4; i++) {
      #pragma unroll
      for (int dw = 0; dw < 3; dw++) {
        const int tp = (dh + 1) * 3 + dw;
        float4 tv = tap[i + dw];
        acc[i].x += tv.x * wf[0 * 9 + tp];
        acc[i].y += tv.y * wf[1 * 9 + tp];
        acc[i].z += tv.z * wf[2 * 9 + tp];
        acc[i].w += tv.w * wf[3 * 9 + tp];
      }
      if (dh == 0) {  // residual: x + conv(x)
        acc[i].x += tap[i + 1].x;
        acc[i].y += tap[i + 1].y;
        acc[i].z += tap[i + 1].z;
        acc[i].w += tap[i + 1].w;
      }
    }
  }
  float s4[4], q4[4];
  #pragma unroll
  for (int i = 0; i < 4; i++) {
    *(float4*)&x1o[(size_t)(gpix + i) * CH + c0] = acc[i];
    s4[i] = acc[i].x + acc[i].y + acc[i].z + acc[i].w;
    q4[i] = acc[i].x * acc[i].x + acc[i].y * acc[i].y + acc[i].z * acc[i].z +
            acc[i].w * acc[i].w;
  }
  #pragma unroll
  for (int m = 1; m <= 8; m <<= 1) {
    #pragma unroll
    for (int i = 0; i < 4; i++) {
      s4[i] += __shfl_xor(s4[i], m, 64);
      q4[i] += __shfl_xor(q4[i], m, 64);
    }
  }
  if ((t & 15) == 0) {
    #pragma unroll
    for (int i = 0; i < 4; i++) { grs[t >> 4][i] = s4[i]; grq[t >> 4][i] = q4[i]; }
  }
  __syncthreads();
  int s3 = st * 3;
  float4 gg = ld4(g + c0);
  float4 bb = ld4(bt + c0);
  #pragma unroll
  for (int i = 0; i < 4; i++) {
    float S = grs[s3][i] + grs[s3 + 1][i] + grs[s3 + 2][i];
    float SS = grq[s3][i] + grq[s3 + 1][i] + grq[s3 + 2][i];
    float mu = S * (1.f / CH);
    float inv = rsqrtf(SS * (1.f / CH) - mu * mu + 1e-5f);
    __align__(8) bf16 tmp[4] = {f2b((acc[i].x - mu) * inv * gg.x + bb.x),
                                f2b((acc[i].y - mu) * inv * gg.y + bb.y),
                                f2b((acc[i].z - mu) * inv * gg.z + bb.z),
                                f2b((acc[i].w - mu) * inv * gg.w + bb.w)};
    *(uint2*)&yo[(size_t)(gpix + i) * CH + c0] = *(uint2*)tmp;
  }
}

// ---------------- strip dwconv, bf16 in/out, 4ch x 4 pixels per thread ----------------
// MODE 1: out = silu(conv+bias)   MODE 2: out += conv+bias
template <int MODE>
__global__ __launch_bounds__(192) void k_dwconv_strip(const bf16* __restrict__ in,
                                                      const float* __restrict__ w,
                                                      const float* __restrict__ bias,
                                                      bf16* __restrict__ out) {
  int t = threadIdx.x;
  int cg = t % 48, st = t / 48;
  int c0 = cg * 4;
  int gpix = blockIdx.x * 16 + st * 4;
  int hw = gpix & (HWSZ - 1);
  int h = hw >> 6, wx = hw & 63;
  float4 w4[9];
  #pragma unroll
  for (int i = 0; i < 9; i++) w4[i] = ld4(w + c0 * 9 + i * 4);
  const float* wf = (const float*)w4;
  float4 bi = ld4(bias + c0);
  float4 acc[4];
  #pragma unroll
  for (int i = 0; i < 4; i++) acc[i] = bi;
  const bf16* base = in + (size_t)gpix * CH + c0;
  #pragma unroll
  for (int dh = -1; dh <= 1; dh++) {
    bool rv = ((unsigned)(h + dh) < HH);
    float4 tap[6];
    #pragma unroll
    for (int c = 0; c < 6; c++) {
      int col = wx - 1 + c;
      bool v = rv && ((unsigned)col < WW);
      tap[c] = v ? ld4(base + (dh * WW + (c - 1)) * CH) : make_float4(0, 0, 0, 0);
    }
    #pragma unroll
    for (int i = 0; i < 4; i++) {
      #pragma unroll
      for (int dw = 0; dw < 3; dw++) {
        const int tp = (dh + 1) * 3 + dw;
        float4 tv = tap[i + dw];
        acc[i].x += tv.x * wf[0 * 9 + tp];
        acc[i].y += tv.y * wf[1 * 9 + tp];
        acc[i].z += tv.z * wf[2 * 9 + tp];
        acc[i].w += tv.w * wf[3 * 9 + tp];
      }
    }
  }
  #pragma unroll
  for (int i = 0; i < 4; i++) {
    bf16* op = out + (size_t)(gpix + i) * CH + c0;
    float a0 = acc[i].x, a1 = acc[i].y, a2 = acc[i].z, a3 = acc[i].w;
    if (MODE == 1) {
      a0 = a0 / (1.f + expf(-a0));
      a1 = a1 / (1.f + expf(-a1));
      a2 = a2 / (1.f + expf(-a2));
      a3 = a3 / (1.f + expf(-a3));
    } else {
      float4 cur = ld4(op);
      a0 += cur.x; a1 += cur.y; a2 += cur.z; a3 += cur.w;
    }
    __align__(8) bf16 tmp[4] = {f2b(a0), f2b(a1), f2b(a2), f2b(a3)};
    *(uint2*)op = *(uint2*)tmp;
  }
}

// ---------------- MFMA bf16 GEMM: tile 128x64, BK=64, 27.6KB LDS ----------------
// BK=64 -> 4 blocks/CU resident; proven round-7 epilogue (scattered stores).
template <int ACT, int MULA, int RES, typename TO>
__global__ __launch_bounds__(256) void k_gemm(const bf16* __restrict__ A,
                                              const bf16* __restrict__ A2,
                                              const bf16* __restrict__ Wt,
                                              const float* __restrict__ bias,
                                              const float* __restrict__ Rsd,
                                              TO* __restrict__ Cout,
                                              int M, int N, int K) {
  __shared__ bf16 As[128][72];
  __shared__ bf16 Bs[64][72];
  int t = threadIdx.x;
  int wave = t >> 6, lane = t & 63;
  int quad = lane >> 4, l16 = lane & 15;
  int m0 = blockIdx.x * 128, n0 = blockIdx.y * 64;
  floatx4 acc[2][4] = {};
  for (int kc = 0; kc < K; kc += 64) {
    #pragma unroll
    for (int i = 0; i < 4; i++) {
      int idx = t + i * 256;
      int m = idx >> 3, ck = (idx & 7) * 8;
      const bf16* pa = &A[(size_t)(m0 + m) * K + kc + ck];
      if (!MULA) {
        *(short8*)&As[m][ck] = *(const short8*)pa;
      } else {
        const bf16* pb = &A2[(size_t)(m0 + m) * K + kc + ck];
        __align__(16) bf16 tmp[8];
        #pragma unroll
        for (int j = 0; j < 8; j++) tmp[j] = f2b(b2f(pa[j]) * b2f(pb[j]));
        *(short8*)&As[m][ck] = *(const short8*)tmp;
      }
    }
    #pragma unroll
    for (int i = 0; i < 2; i++) {
      int idx = t + i * 256;
      int n = idx >> 3, ck = (idx & 7) * 8;
      *(short8*)&Bs[n][ck] = *(const short8*)&Wt[(size_t)(n0 + n) * K + kc + ck];
    }
    __syncthreads();
    #pragma unroll
    for (int ks = 0; ks < 2; ks++) {
      short8 af[2], bfr[4];
      #pragma unroll
      for (int i = 0; i < 2; i++)
        af[i] = *(const short8*)&As[wave * 32 + i * 16 + l16][ks * 32 + quad * 8];
      #pragma unroll
      for (int j = 0; j < 4; j++)
        bfr[j] = *(const short8*)&Bs[j * 16 + l16][ks * 32 + quad * 8];
      #pragma unroll
      for (int i = 0; i < 2; i++)
        #pragma unroll
        for (int j = 0; j < 4; j++)
          acc[i][j] = __builtin_amdgcn_mfma_f32_16x16x32_bf16(af[i], bfr[j], acc[i][j], 0, 0, 0);
    }
    __syncthreads();
  }
  #pragma unroll
  for (int i = 0; i < 2; i++) {
    #pragma unroll
    for (int j = 0; j < 4; j++) {
      int n = n0 + j * 16 + l16;
      float bn = bias[n];
      #pragma unroll
      for (int r = 0; r < 4; r++) {
        int m = m0 + wave * 32 + i * 16 + quad * 4 + r;
        float v = actf<ACT>(acc[i][j][r] + bn);
        if (RES) v += Rsd[(size_t)m * N + n];
        stv(&Cout[(size_t)m * N + n], v);
      }
    }
  }
}

// dual-output GEMM (K=192, BK=64, N-tile=96): N=384 as two 192 halves, 2 tiles per half.
// 96-wide tiles never straddle the half boundary; A-tile restaged 4x (was 6x).
template <int ACTA, int ACTB, int KMEAN>
__global__ __launch_bounds__(256) void k_gemm_dual(const bf16* __restrict__ A,
                                                   const bf16* __restrict__ WtA,
                                                   const float* __restrict__ biasA,
                                                   const bf16* __restrict__ WtB,
                                                   const float* __restrict__ biasB,
                                                   bf16* __restrict__ OutA,
                                                   bf16* __restrict__ OutB,
                                                   float* __restrict__ KM,
                                                   int K) {
  __shared__ bf16 As[128][72];
  __shared__ bf16 Bs[96][72];
  __shared__ float colsum[96];
  int t = threadIdx.x;
  int wave = t >> 6, lane = t & 63;
  int quad = lane >> 4, l16 = lane & 15;
  int m0 = blockIdx.x * 128, n0 = blockIdx.y * 96;
  int half = n0 >= 192;
  int n0l = half ? n0 - 192 : n0;
  const bf16* Wt = half ? WtB : WtA;
  const float* bias = half ? biasB : biasA;
  bf16* Out = half ? OutB : OutA;
  if (KMEAN && half && t < 96) colsum[t] = 0.f;
  floatx4 acc[2][6] = {};
  for (int kc = 0; kc < CH; kc += 64) {
    #pragma unroll
    for (int i = 0; i < 4; i++) {
      int idx = t + i * 256;
      int m = idx >> 3, ck = (idx & 7) * 8;
      *(short8*)&As[m][ck] = *(const short8*)&A[(size_t)(m0 + m) * CH + kc + ck];
    }
    #pragma unroll
    for (int i = 0; i < 3; i++) {
      int idx = t + i * 256;
      int n = idx >> 3, ck = (idx & 7) * 8;
      *(short8*)&Bs[n][ck] = *(const short8*)&Wt[(size_t)(n0l + n) * CH + kc + ck];
    }
    __syncthreads();
    #pragma unroll
    for (int ks = 0; ks < 2; ks++) {
      short8 af[2], bfr[6];
      #pragma unroll
      for (int i = 0; i < 2; i++)
        af[i] = *(const short8*)&As[wave * 32 + i * 16 + l16][ks * 32 + quad * 8];
      #pragma unroll
      for (int j = 0; j < 6; j++)
        bfr[j] = *(const short8*)&Bs[j * 16 + l16][ks * 32 + quad * 8];
      #pragma unroll
      for (int i = 0; i < 2; i++)
        #pragma unroll
        for (int j = 0; j < 6; j++)
          acc[i][j] = __builtin_amdgcn_mfma_f32_16x16x32_bf16(af[i], bfr[j], acc[i][j], 0, 0, 0);
    }
    __syncthreads();
  }
  #pragma unroll
  for (int j = 0; j < 6; j++) {
    int nl = n0l + j * 16 + l16;
    float bn = bias[nl];
    float csum = 0.f;
    #pragma unroll
    for (int i = 0; i < 2; i++) {
      #pragma unroll
      for (int r = 0; r < 4; r++) {
        int m = m0 + wave * 32 + i * 16 + quad * 4 + r;
        float v = half ? actf<ACTB>(acc[i][j][r] + bn) : actf<ACTA>(acc[i][j][r] + bn);
        if (KMEAN && half) csum += v;
        Out[(size_t)m * CH + nl] = f2b(v);
      }
    }
    if (KMEAN && half) atomicAdd(&colsum[j * 16 + l16], csum);
  }
  if (KMEAN && half) {
    __syncthreads();
    if (t < 96) {
      int b = m0 >> 12;
      atomicAdd(&KM[b * CH + n0l + t], colsum[t] * (1.f / 4096.f));
    }
  }
}

// ---------------- kv via MFMA: kv[d][e] = sum_n K_rope[n][d] * V[n][e] ----------------
__global__ __launch_bounds__(256) void k_kv(const bf16* __restrict__ k,
                                            const bf16* __restrict__ v,
                                            const float* __restrict__ cosT,
                                            const float* __restrict__ sinT,
                                            float* __restrict__ kv) {
  int bh = blockIdx.x;
  int b = bh / NHEADS, hd = bh % NHEADS;
  int chunk0 = blockIdx.y * 512;
  __shared__ __align__(16) bf16 kst[32][280];
  __shared__ __align__(16) bf16 vst[32][280];
  int t = threadIdx.x;
  int wave = t >> 6, lane = t & 63;
  int quad = lane >> 4, l16 = lane & 15;
  int dh = wave >> 1, eh = wave & 1;
  floatx4 acc = {};
  for (int sub = 0; sub < 2; sub++) {
    int n0 = chunk0 + sub * 256;
    #pragma unroll
    for (int it = 0; it < 4; it++) {
      int idx = t + it * 256;            // 0..1023 = 256 rows x 4 c-groups
      int row = idx >> 2, c0 = (idx & 3) * 8;
      int n = n0 + row;
      size_t gi = ((size_t)(b * HWSZ + n)) * CH + hd * HDIM + c0;
      short8 vv = *(const short8*)&v[gi];
      #pragma unroll
      for (int j = 0; j < 8; j++) vst[c0 + j][row] = ((const bf16*)&vv)[j];
      float4 klo = ld4(&k[gi]);
      float4 khi = ld4(&k[gi + 4]);
      int prb = hd * 16 + (c0 >> 1);
      float cs0 = cosT[(size_t)(prb + 0) * HWSZ + n];
      float sn0 = sinT[(size_t)(prb + 0) * HWSZ + n];
      float cs1 = cosT[(size_t)(prb + 1) * HWSZ + n];
      float sn1 = sinT[(size_t)(prb + 1) * HWSZ + n];
      float cs2 = cosT[(size_t)(prb + 2) * HWSZ + n];
      float sn2 = sinT[(size_t)(prb + 2) * HWSZ + n];
      float cs3 = cosT[(size_t)(prb + 3) * HWSZ + n];
      float sn3 = sinT[(size_t)(prb + 3) * HWSZ + n];
      kst[c0 + 0][row] = f2b(klo.x * cs0 - klo.y * sn0);
      kst[c0 + 1][row] = f2b(klo.x * sn0 + klo.y * cs0);
      kst[c0 + 2][row] = f2b(klo.z * cs1 - klo.w * sn1);
      kst[c0 + 3][row] = f2b(klo.z * sn1 + klo.w * cs1);
      kst[c0 + 4][row] = f2b(khi.x * cs2 - khi.y * sn2);
      kst[c0 + 5][row] = f2b(khi.x * sn2 + khi.y * cs2);
      kst[c0 + 6][row] = f2b(khi.z * cs3 - khi.w * sn3);
      kst[c0 + 7][row] = f2b(khi.z * sn3 + khi.w * cs3);
    }
    __syncthreads();
    #pragma unroll
    for (int ks = 0; ks < 8; ks++) {
      short8 af = *(const short8*)&kst[dh * 16 + l16][ks * 32 + quad * 8];
      short8 bfr = *(const short8*)&vst[eh * 16 + l16][ks * 32 + quad * 8];
      acc = __builtin_amdgcn_mfma_f32_16x16x32_bf16(af, bfr, acc, 0, 0, 0);
    }
    __syncthreads();
  }
  // C/D layout: col = lane&15, row = quad*4 + r  (m89-verified)
  int d = dh * 16 + quad * 4;
  int e = eh * 16 + l16;
  float* dst = kv + (size_t)bh * (HDIM * HDIM) + (size_t)d * HDIM + e;
  const float sc = 1.f / 4096.f;
  #pragma unroll
  for (int r = 0; r < 4; r++) atomicAdd(dst + r * HDIM, acc[r] * sc);
}

// ---------------- attn via MFMA: out = (rope(q) @ kv) * zi ----------------
__global__ __launch_bounds__(256) void k_attn(const bf16* __restrict__ q,
                                              const float* __restrict__ kv,
                                              const float* __restrict__ kmean,
                                              const float* __restrict__ cosT,
                                              const float* __restrict__ sinT,
                                              bf16* __restrict__ attn) {
  int hd = blockIdx.y, b = blockIdx.z;
  int t = threadIdx.x;
  int hw = blockIdx.x * 256 + t;
  int bh = b * NHEADS + hd;
  __shared__ __align__(16) bf16 As[256][40];
  __shared__ __align__(16) bf16 Bs[32][40];
  int wave = t >> 6, lane = t & 63;
  int quad = lane >> 4, l16 = lane & 15;
  // stage kv^T -> Bs[e][d] (bf16)
  {
    int e = t >> 3, d0 = (t & 7) * 4;
    const float* kvp = kv + (size_t)bh * 1024;
    __align__(8) bf16 tmp[4] = {f2b(kvp[(d0 + 0) * 32 + e]), f2b(kvp[(d0 + 1) * 32 + e]),
                                f2b(kvp[(d0 + 2) * 32 + e]), f2b(kvp[(d0 + 3) * 32 + e])};
    *(uint2*)&Bs[e][d0] = *(uint2*)tmp;
  }
  // per-pixel: z (pre-rope) and rope(q) -> As[t][:]
  int pix = b * HWSZ + hw;
  const bf16* qp = q + (size_t)pix * CH + hd * HDIM;
  float qv[32];
  #pragma unroll
  for (int i = 0; i < 32; i++) qv[i] = b2f(qp[i]);
  const float* km = kmean + b * CH + hd * HDIM;
  float z = 1e-6f;
  #pragma unroll
  for (int d = 0; d < 32; d++) z += qv[d] * km[d];
  float zi = 1.f / z;
  __align__(16) bf16 ar[32];
  #pragma unroll
  for (int p = 0; p < 16; p++) {
    float cs = cosT[(size_t)(hd * 16 + p) * HWSZ + hw];
    float sn = sinT[(size_t)(hd * 16 + p) * HWSZ + hw];
    float re = qv[2 * p], im = qv[2 * p + 1];
    ar[2 * p] = f2b(re * cs - im * sn);
    ar[2 * p + 1] = f2b(re * sn + im * cs);
  }
  #pragma unroll
  for (int i = 0; i < 4; i++) *(short8*)&As[t][i * 8] = *(const short8*)&ar[i * 8];
  __syncthreads();
  // MFMA: wave w owns pixels [w*64, w*64+64): 4 m-tiles x 2 n-tiles
  short8 af[4], bfr[2];
  #pragma unroll
  for (int nt = 0; nt < 2; nt++) bfr[nt] = *(const short8*)&Bs[nt * 16 + l16][quad * 8];
  #pragma unroll
  for (int mt = 0; mt < 4; mt++)
    af[mt] = *(const short8*)&As[wave * 64 + mt * 16 + l16][quad * 8];
  floatx4 acc[4][2] = {};
  #pragma unroll
  for (int mt = 0; mt < 4; mt++)
    #pragma unroll
    for (int nt = 0; nt < 2; nt++)
      acc[mt][nt] = __builtin_amdgcn_mfma_f32_16x16x32_bf16(af[mt], bfr[nt], acc[mt][nt], 0, 0, 0);
  __syncthreads();
  // C restage into As: row = pixel (wave-local), col = e
  #pragma unroll
  for (int mt = 0; mt < 4; mt++)
    #pragma unroll
    for (int nt = 0; nt < 2; nt++) {
      int row = wave * 64 + mt * 16 + quad * 4;
      int col = nt * 16 + l16;
      #pragma unroll
      for (int r = 0; r < 4; r++) As[row + r][col] = f2b(acc[mt][nt][r]);
    }
  __syncthreads();
  // each thread: read its own pixel row, scale by in-register zi, coalesced store
  bf16* op = attn + (size_t)pix * CH + hd * HDIM;
  #pragma unroll
  for (int i = 0; i < 4; i++) {
    short8 vv = *(const short8*)&As[t][i * 8];
    __align__(16) bf16 tmp[8];
    #pragma unroll
    for (int j = 0; j < 8; j++) tmp[j] = f2b(b2f(((const bf16*)&vv)[j]) * zi);
    *(short8*)&op[i * 8] = *(const short8*)tmp;
  }
}

extern "C" void kernel_launch(void* const* d_in, const int* in_sizes, int n_in,
                              void* d_out, int out_size, void* d_ws, size_t ws_size,
                              hipStream_t stream) {
  const float* x = (const float*)d_in[0];
  const float* cpe1w = (const float*)d_in[1];
  const float* cpe1b = (const float*)d_in[2];
  const float* n1w = (const float*)d_in[3];
  const float* n1b = (const float*)d_in[4];
  const float* apw = (const float*)d_in[5];
  const float* apb = (const float*)d_in[6];
  const float* ipw = (const float*)d_in[7];
  const float* ipb = (const float*)d_in[8];
  const float* dwcw = (const float*)d_in[9];
  const float* dwcb = (const float*)d_in[10];
  const float* qkw = (const float*)d_in[11];
  const float* qkb = (const float*)d_in[12];
  const float* lepw = (const float*)d_in[13];
  const float* lepb = (const float*)d_in[14];
  const float* opw = (const float*)d_in[15];
  const float* opb = (const float*)d_in[16];
  const float* cpe2w = (const float*)d_in[17];
  const float* cpe2b = (const float*)d_in[18];
  const float* n2w = (const float*)d_in[19];
  const float* n2b = (const float*)d_in[20];
  const float* f1w = (const float*)d_in[21];
  const float* f1b = (const float*)d_in[22];
  const float* f2w = (const float*)d_in[23];
  const float* f2b = (const float*)d_in[24];
  float* out = (float*)d_out;

  float* ws = (float*)d_ws;
  const size_t S = (size_t)NPIX * CH;
  float* FA = ws;                       // fp32: x NHWC -> (bf16 k/attn scratch) -> x3 -> final
  float* FB = ws + S;                   // fp32: x1 -> (bf16 MLP hidden stripes)
  bf16* barena = (bf16*)(ws + 2 * S);
  bf16* b0 = barena;                    // y -> t/v -> y4
  bf16* b1 = barena + S;                // act_res
  bf16* b2 = barena + 2 * S;            // y2 -> q -> x2
  bf16* KB = (bf16*)FA;                 // k, then attn (FA dead between cpe1 and cpe2)
  float* COS = ws + 2 * S + 3 * S / 2;
  float* SIN = COS + (size_t)NPAIR * HWSZ;
  float* KV = SIN + (size_t)NPAIR * HWSZ;
  float* KM = KV + BQ * NHEADS * HDIM * HDIM;
  bf16* WB = (bf16*)(KM + BQ * CH);     // bf16 weight arena (479232 elems)
  bf16* apw16 = WB;
  bf16* ipw16 = WB + 36864;
  bf16* qkw16 = WB + 73728;             // [384][192]; halves at +0 and +36864
  bf16* opw16 = WB + 147456;
  bf16* f1w16 = WB + 184320;
  bf16* f2w16 = WB + 331776;
  bf16* HIDB = (bf16*)FB;

  dim3 tb(32, 8);
  // 0. weights -> bf16 once
  k_wcvt<<<dim3((WTOT / 4 + 255) / 256), dim3(256), 0, stream>>>(
      apw, ipw, qkw, opw, f1w, f2w, WB);
  // 1. transpose input NCHW -> NHWC fp32
  k_transpose_in<<<dim3(6, 128, BQ), tb, 0, stream>>>(x, FA);
  // 2. rope tables [pair][hw]
  k_rope<<<dim3(NPAIR * HWSZ / 256), dim3(256), 0, stream>>>(COS, SIN);
  // 3. x1 = x + cpe1(x); y = LN1(x1)   [fused]
  k_cpe_ln<float><<<dim3(NPIX / 16), dim3(192), 0, stream>>>(FA, cpe1w, cpe1b, n1w, n1b, FB, b0);
  // 4. act_res = silu(act_proj(y)); y2 = in_proj(y)
  k_gemm_dual<1, 0, 0><<<dim3(NPIX / 128, 4), dim3(256), 0, stream>>>(
      b0, apw16, apb, ipw16, ipb, b1, b2, nullptr, CH);
  // 5. t = v = silu(dwc(y2))
  k_dwconv_strip<1><<<dim3(NPIX / 16), dim3(192), 0, stream>>>(b2, dwcw, dwcb, b0);
  // 6. q,k = elu(t @ qk_w^T + qk_b)+1 ; kmean fused into k epilogue
  hipMemsetAsync(KM, 0, (size_t)BQ * CH * sizeof(float), stream);
  k_gemm_dual<2, 2, 1><<<dim3(NPIX / 128, 4), dim3(256), 0, stream>>>(
      b0, qkw16, qkb, qkw16 + CH * CH, qkb + CH, b2, KB, KM, CH);
  // 7. kv accumulate (fused rope, MFMA, 512 rows/block)
  hipMemsetAsync(KV, 0, (size_t)BQ * NHEADS * HDIM * HDIM * sizeof(float), stream);
  k_kv<<<dim3(BQ * NHEADS, 8), dim3(256), 0, stream>>>(KB, b0, COS, SIN, KV);
  // 8. attn = (q_rope @ kv) * z  -> KB (k dead)
  k_attn<<<dim3(HWSZ / 256, NHEADS, BQ), dim3(256), 0, stream>>>(b2, KV, KM, COS, SIN, KB);
  // 9. attn += lepe(v)
  k_dwconv_strip<2><<<dim3(NPIX / 16), dim3(192), 0, stream>>>(b0, lepw, lepb, KB);
  // 10. x2 = x1 + out_proj(attn * act_res)  -> b2 (bf16)
  k_gemm<0, 1, 1, bf16><<<dim3(NPIX / 128, 3), dim3(256), 0, stream>>>(
      KB, b1, opw16, opb, FB, b2, NPIX, CH, CH);
  // 11. x3 = x2 + cpe2(x2); y4 = LN2(x3)   [fused]
  k_cpe_ln<bf16><<<dim3(NPIX / 16), dim3(192), 0, stream>>>(b2, cpe2w, cpe2b, n2w, n2b, FA, b0);
  // 12. MLP in 2 stripes; hidden bf16 stripe lives in FB (x1 dead)
  for (int s = 0; s < 2; s++) {
    size_t off = (size_t)s * (NPIX / 2) * CH;
    k_gemm<3, 0, 0, bf16><<<dim3((NPIX / 2) / 128, HID / 64), dim3(256), 0, stream>>>(
        b0 + off, (const bf16*)nullptr, f1w16, f1b, (const float*)nullptr, HIDB, NPIX / 2, HID, CH);
    k_gemm<0, 0, 1, float><<<dim3((NPIX / 2) / 128, 3), dim3(256), 0, stream>>>(
        HIDB, (const bf16*)nullptr, f2w16, f2b, FA + off, FA + off, NPIX / 2, CH, HID);
  }
  // 13. final transpose NHWC fp32 -> NCHW fp32
  k_transpose_out<<<dim3(6, 128, BQ), tb, 0, stream>>>(FA, out);
}

// Round 14
// 526.168 us; speedup vs baseline: 1.1956x; 1.1029x over previous
//
#include <hip/hip_runtime.h>
#include <hip/hip_bf16.h>

#define BQ 16
#define CH 192
#define HH 64
#define WW 64
#define HWSZ 4096
#define NPIX 65536
#define NHEADS 6
#define HDIM 32
#define NPAIR 96
#define KMAXR 48
#define HID 768

typedef __hip_bfloat16 bf16;
typedef __attribute__((ext_vector_type(8))) short short8;
typedef __attribute__((ext_vector_type(4))) float floatx4;

// direct global->LDS DMA, 16B per lane; LDS dest = wave-uniform base + lane*16
#define GLDS16(gp, lp)                                                        \
  __builtin_amdgcn_global_load_lds(                                           \
      (const __attribute__((address_space(1))) void*)(gp),                    \
      (__attribute__((address_space(3))) void*)(lp), 16, 0, 0)

static __device__ __forceinline__ float b2f(bf16 v) { return __bfloat162float(v); }
static __device__ __forceinline__ bf16 f2b(float v) { return __float2bfloat16(v); }

static __device__ __forceinline__ float4 ld4(const float* p) { return *(const float4*)p; }
static __device__ __forceinline__ float4 ld4(const bf16* p) {
  uint2 u = *(const uint2*)p;
  return make_float4(__uint_as_float(u.x << 16), __uint_as_float(u.x & 0xffff0000u),
                     __uint_as_float(u.y << 16), __uint_as_float(u.y & 0xffff0000u));
}

template <int ACT>
static __device__ __forceinline__ float actf(float v) {
  if (ACT == 1) return v / (1.f + expf(-v));                               // silu
  if (ACT == 2) return (v > 0.f) ? v + 1.f : expf(v);                      // elu+1
  if (ACT == 3) return 0.5f * v * (1.f + erff(v * 0.70710678118654752f));  // gelu
  return v;
}
static __device__ __forceinline__ void stv(float* p, float v) { *p = v; }
static __device__ __forceinline__ void stv(bf16* p, float v) { *p = __float2bfloat16(v); }

// ---------------- transpose NCHW -> NHWC (fp32) ----------------
__global__ __launch_bounds__(256) void k_transpose_in(const float* __restrict__ in,
                                                      float* __restrict__ out) {
  __shared__ float tile[32][33];
  int c0 = blockIdx.x * 32, hw0 = blockIdx.y * 32, b = blockIdx.z;
  int tx = threadIdx.x, ty = threadIdx.y;
  const float* src = in + (size_t)b * CH * HWSZ;
  #pragma unroll
  for (int j = 0; j < 32; j += 8)
    tile[ty + j][tx] = src[(size_t)(c0 + ty + j) * HWSZ + hw0 + tx];
  __syncthreads();
  float* dst = out + (size_t)b * HWSZ * CH;
  #pragma unroll
  for (int j = 0; j < 32; j += 8)
    dst[(size_t)(hw0 + ty + j) * CH + c0 + tx] = tile[tx][ty + j];
}

// ---------------- transpose NHWC -> NCHW (fp32) ----------------
__global__ __launch_bounds__(256) void k_transpose_out(const float* __restrict__ in,
                                                       float* __restrict__ out) {
  __shared__ float tile[32][33];
  int c0 = blockIdx.x * 32, hw0 = blockIdx.y * 32, b = blockIdx.z;
  int tx = threadIdx.x, ty = threadIdx.y;
  const float* src = in + (size_t)b * HWSZ * CH;
  #pragma unroll
  for (int j = 0; j < 32; j += 8)
    tile[ty + j][tx] = src[(size_t)(hw0 + ty + j) * CH + c0 + tx];
  __syncthreads();
  float* dst = out + (size_t)b * CH * HWSZ;
  #pragma unroll
  for (int j = 0; j < 32; j += 8)
    dst[(size_t)(c0 + ty + j) * HWSZ + hw0 + tx] = tile[tx][ty + j];
}

// ---------------- RoPE tables, layout [pair][hw] ----------------
__global__ __launch_bounds__(256) void k_rope(float* __restrict__ cosT, float* __restrict__ sinT) {
  int i = blockIdx.x * 256 + threadIdx.x;
  if (i >= NPAIR * HWSZ) return;
  int hw = i & (HWSZ - 1);
  int p = i >> 12;
  int h = hw >> 6, w = hw & 63;
  int j = (p < KMAXR) ? p : p - KMAXR;
  float theta = powf(10000.f, -(float)j / (float)KMAXR);
  float pos = (p < KMAXR) ? (float)h : (float)w;
  float ang = pos * theta;
  cosT[i] = cosf(ang);
  sinT[i] = sinf(ang);
}

// ---------------- one-shot fp32 -> bf16 weight conversion ----------------
// regions (element offsets): ap 0, ip 36864, qk 73728, op 147456, f1 184320, f2 331776
#define WTOT 479232
__global__ __launch_bounds__(256) void k_wcvt(const float* __restrict__ ap,
                                              const float* __restrict__ ip,
                                              const float* __restrict__ qk,
                                              const float* __restrict__ op,
                                              const float* __restrict__ f1,
                                              const float* __restrict__ f2,
                                              bf16* __restrict__ o) {
  int i = (blockIdx.x * 256 + threadIdx.x) * 4;
  if (i >= WTOT) return;
  const float* src;
  int off;
  if (i < 36864)       { src = ap; off = 0; }
  else if (i < 73728)  { src = ip; off = 36864; }
  else if (i < 147456) { src = qk; off = 73728; }
  else if (i < 184320) { src = op; off = 147456; }
  else if (i < 331776) { src = f1; off = 184320; }
  else                 { src = f2; off = 331776; }
  float4 v = ld4(src + (i - off));
  __align__(8) bf16 t4[4] = {f2b(v.x), f2b(v.y), f2b(v.z), f2b(v.w)};
  *(uint2*)&o[i] = *(uint2*)t4;
}

// ---------------- fused dwconv(residual) + LayerNorm (strip) ----------------
template <typename TI>
__global__ __launch_bounds__(192) void k_cpe_ln(const TI* __restrict__ in,
                                                const float* __restrict__ w,
                                                const float* __restrict__ bias,
                                                const float* __restrict__ g,
                                                const float* __restrict__ bt,
                                                float* __restrict__ x1o,
                                                bf16* __restrict__ yo) {
  __shared__ float grs[12][4], grq[12][4];
  int t = threadIdx.x;
  int cg = t % 48, st = t / 48;
  int c0 = cg * 4;
  int gpix = blockIdx.x * 16 + st * 4;  // first pixel of this strip (incl. batch)
  int hw = gpix & (HWSZ - 1);
  int h = hw >> 6, wx = hw & 63;        // strip covers cols wx..wx+3 of row h
  float4 w4[9];
  #pragma unroll
  for (int i = 0; i < 9; i++) w4[i] = ld4(w + c0 * 9 + i * 4);
  const float* wf = (const float*)w4;
  float4 bi = ld4(bias + c0);
  float4 acc[4];
  #pragma unroll
  for (int i = 0; i < 4; i++) acc[i] = bi;
  const TI* base = in + (size_t)gpix * CH + c0;
  #pragma unroll
  for (int dh = -1; dh <= 1; dh++) {
    bool rv = ((unsigned)(h + dh) < HH);
    float4 tap[6];
    #pragma unroll
    for (int c = 0; c < 6; c++) {
      int col = wx - 1 + c;
      bool v = rv && ((unsigned)col < WW);
      tap[c] = v ? ld4(base + (dh * WW + (c - 1)) * CH) : make_float4(0, 0, 0, 0);
    }
    #pragma unroll
    for (int i = 0; i < 4; i++) {
      #pragma unroll
      for (int dw = 0; dw < 3; dw++) {
        const int tp = (dh + 1) * 3 + dw;
        float4 tv = tap[i + dw];
        acc[i].x += tv.x * wf[0 * 9 + tp];
        acc[i].y += tv.y * wf[1 * 9 + tp];
        acc[i].z += tv.z * wf[2 * 9 + tp];
        acc[i].w += tv.w * wf[3 * 9 + tp];
      }
      if (dh == 0) {  // residual: x + conv(x)
        acc[i].x += tap[i + 1].x;
        acc[i].y += tap[i + 1].y;
        acc[i].z += tap[i + 1].z;
        acc[i].w += tap[i + 1].w;
      }
    }
  }
  float s4[4], q4[4];
  #pragma unroll
  for (int i = 0; i < 4; i++) {
    *(float4*)&x1o[(size_t)(gpix + i) * CH + c0] = acc[i];
    s4[i] = acc[i].x + acc[i].y + acc[i].z + acc[i].w;
    q4[i] = acc[i].x * acc[i].x + acc[i].y * acc[i].y + acc[i].z * acc[i].z +
            acc[i].w * acc[i].w;
  }
  #pragma unroll
  for (int m = 1; m <= 8; m <<= 1) {
    #pragma unroll
    for (int i = 0; i < 4; i++) {
      s4[i] += __shfl_xor(s4[i], m, 64);
      q4[i] += __shfl_xor(q4[i], m, 64);
    }
  }
  if ((t & 15) == 0) {
    #pragma unroll
    for (int i = 0; i < 4; i++) { grs[t >> 4][i] = s4[i]; grq[t >> 4][i] = q4[i]; }
  }
  __syncthreads();
  int s3 = st * 3;
  float4 gg = ld4(g + c0);
  float4 bb = ld4(bt + c0);
  #pragma unroll
  for (int i = 0; i < 4; i++) {
    float S = grs[s3][i] + grs[s3 + 1][i] + grs[s3 + 2][i];
    float SS = grq[s3][i] + grq[s3 + 1][i] + grq[s3 + 2][i];
    float mu = S * (1.f / CH);
    float inv = rsqrtf(SS * (1.f / CH) - mu * mu + 1e-5f);
    __align__(8) bf16 tmp[4] = {f2b((acc[i].x - mu) * inv * gg.x + bb.x),
                                f2b((acc[i].y - mu) * inv * gg.y + bb.y),
                                f2b((acc[i].z - mu) * inv * gg.z + bb.z),
                                f2b((acc[i].w - mu) * inv * gg.w + bb.w)};
    *(uint2*)&yo[(size_t)(gpix + i) * CH + c0] = *(uint2*)tmp;
  }
}

// ---------------- strip dwconv, bf16 in/out, 4ch x 4 pixels per thread ----------------
// MODE 1: out = silu(conv+bias)   MODE 2: out += conv+bias
template <int MODE>
__global__ __launch_bounds__(192) void k_dwconv_strip(const bf16* __restrict__ in,
                                                      const float* __restrict__ w,
                                                      const float* __restrict__ bias,
                                                      bf16* __restrict__ out) {
  int t = threadIdx.x;
  int cg = t % 48, st = t / 48;
  int c0 = cg * 4;
  int gpix = blockIdx.x * 16 + st * 4;
  int hw = gpix & (HWSZ - 1);
  int h = hw >> 6, wx = hw & 63;
  float4 w4[9];
  #pragma unroll
  for (int i = 0; i < 9; i++) w4[i] = ld4(w + c0 * 9 + i * 4);
  const float* wf = (const float*)w4;
  float4 bi = ld4(bias + c0);
  float4 acc[4];
  #pragma unroll
  for (int i = 0; i < 4; i++) acc[i] = bi;
  const bf16* base = in + (size_t)gpix * CH + c0;
  #pragma unroll
  for (int dh = -1; dh <= 1; dh++) {
    bool rv = ((unsigned)(h + dh) < HH);
    float4 tap[6];
    #pragma unroll
    for (int c = 0; c < 6; c++) {
      int col = wx - 1 + c;
      bool v = rv && ((unsigned)col < WW);
      tap[c] = v ? ld4(base + (dh * WW + (c - 1)) * CH) : make_float4(0, 0, 0, 0);
    }
    #pragma unroll
    for (int i = 0; i < 4; i++) {
      #pragma unroll
      for (int dw = 0; dw < 3; dw++) {
        const int tp = (dh + 1) * 3 + dw;
        float4 tv = tap[i + dw];
        acc[i].x += tv.x * wf[0 * 9 + tp];
        acc[i].y += tv.y * wf[1 * 9 + tp];
        acc[i].z += tv.z * wf[2 * 9 + tp];
        acc[i].w += tv.w * wf[3 * 9 + tp];
      }
    }
  }
  #pragma unroll
  for (int i = 0; i < 4; i++) {
    bf16* op = out + (size_t)(gpix + i) * CH + c0;
    float a0 = acc[i].x, a1 = acc[i].y, a2 = acc[i].z, a3 = acc[i].w;
    if (MODE == 1) {
      a0 = a0 / (1.f + expf(-a0));
      a1 = a1 / (1.f + expf(-a1));
      a2 = a2 / (1.f + expf(-a2));
      a3 = a3 / (1.f + expf(-a3));
    } else {
      float4 cur = ld4(op);
      a0 += cur.x; a1 += cur.y; a2 += cur.z; a3 += cur.w;
    }
    __align__(8) bf16 tmp[4] = {f2b(a0), f2b(a1), f2b(a2), f2b(a3)};
    *(uint2*)op = *(uint2*)tmp;
  }
}

// ---------------- MFMA bf16 GEMM: tile 128x64, BK=64 ----------------
// Non-MULA: A/B staged via global_load_lds (linear LDS, XOR-swizzled SOURCE addr,
// swizzled fragment read). MULA: A needs VALU (attn*act_res) -> padded reg path; B DMA.
template <int ACT, int MULA, int RES, typename TO>
__global__ __launch_bounds__(256) void k_gemm(const bf16* __restrict__ A,
                                              const bf16* __restrict__ A2,
                                              const bf16* __restrict__ Wt,
                                              const float* __restrict__ bias,
                                              const float* __restrict__ Rsd,
                                              TO* __restrict__ Cout,
                                              int M, int N, int K) {
  constexpr int AST = MULA ? 72 : 64;
  __shared__ bf16 As[128 * AST];
  __shared__ bf16 Bs[64 * 64];
  int t = threadIdx.x;
  int wave = t >> 6, lane = t & 63;
  int quad = lane >> 4, l16 = lane & 15;
  int m0 = blockIdx.x * 128, n0 = blockIdx.y * 64;
  floatx4 acc[2][4] = {};
  for (int kc = 0; kc < K; kc += 64) {
    if (!MULA) {
      #pragma unroll
      for (int i = 0; i < 4; i++) {
        int rb = (i * 4 + wave) * 8;
        int m = rb + (lane >> 3);
        int u = (lane & 7) ^ (m & 7);
        GLDS16(&A[(size_t)(m0 + m) * K + kc + u * 8], &As[rb * 64]);
      }
    } else {
      #pragma unroll
      for (int i = 0; i < 4; i++) {
        int idx = t + i * 256;
        int m = idx >> 3, ck = (idx & 7) * 8;
        const bf16* pa = &A[(size_t)(m0 + m) * K + kc + ck];
        const bf16* pb = &A2[(size_t)(m0 + m) * K + kc + ck];
        __align__(16) bf16 tmp[8];
        #pragma unroll
        for (int j = 0; j < 8; j++) tmp[j] = f2b(b2f(pa[j]) * b2f(pb[j]));
        *(short8*)&As[m * AST + ck] = *(const short8*)tmp;
      }
    }
    #pragma unroll
    for (int i = 0; i < 2; i++) {
      int rb = (i * 4 + wave) * 8;
      int n = rb + (lane >> 3);
      int u = (lane & 7) ^ (n & 7);
      GLDS16(&Wt[(size_t)(n0 + n) * K + kc + u * 8], &Bs[rb * 64]);
    }
    __syncthreads();
    #pragma unroll
    for (int ks = 0; ks < 2; ks++) {
      short8 af[2], bfr[4];
      #pragma unroll
      for (int i = 0; i < 2; i++) {
        int row = wave * 32 + i * 16 + l16;
        int sc = MULA ? (ks * 32 + quad * 8) : (((ks * 4 + quad) ^ (row & 7)) * 8);
        af[i] = *(const short8*)&As[row * AST + sc];
      }
      #pragma unroll
      for (int j = 0; j < 4; j++) {
        int row = j * 16 + l16;
        bfr[j] = *(const short8*)&Bs[row * 64 + ((ks * 4 + quad) ^ (row & 7)) * 8];
      }
      #pragma unroll
      for (int i = 0; i < 2; i++)
        #pragma unroll
        for (int j = 0; j < 4; j++)
          acc[i][j] = __builtin_amdgcn_mfma_f32_16x16x32_bf16(af[i], bfr[j], acc[i][j], 0, 0, 0);
    }
    __syncthreads();
  }
  #pragma unroll
  for (int i = 0; i < 2; i++) {
    #pragma unroll
    for (int j = 0; j < 4; j++) {
      int n = n0 + j * 16 + l16;
      float bn = bias[n];
      #pragma unroll
      for (int r = 0; r < 4; r++) {
        int m = m0 + wave * 32 + i * 16 + quad * 4 + r;
        float v = actf<ACT>(acc[i][j][r] + bn);
        if (RES) v += Rsd[(size_t)m * N + n];
        stv(&Cout[(size_t)m * N + n], v);
      }
    }
  }
}

// dual-output GEMM (K=192, BK=64, N-tile=96): global_load_lds staging both operands.
template <int ACTA, int ACTB, int KMEAN>
__global__ __launch_bounds__(256) void k_gemm_dual(const bf16* __restrict__ A,
                                                   const bf16* __restrict__ WtA,
                                                   const float* __restrict__ biasA,
                                                   const bf16* __restrict__ WtB,
                                                   const float* __restrict__ biasB,
                                                   bf16* __restrict__ OutA,
                                                   bf16* __restrict__ OutB,
                                                   float* __restrict__ KM,
                                                   int K) {
  __shared__ bf16 As[128 * 64];
  __shared__ bf16 Bs[96 * 64];
  __shared__ float colsum[96];
  int t = threadIdx.x;
  int wave = t >> 6, lane = t & 63;
  int quad = lane >> 4, l16 = lane & 15;
  int m0 = blockIdx.x * 128, n0 = blockIdx.y * 96;
  int half = n0 >= 192;
  int n0l = half ? n0 - 192 : n0;
  const bf16* Wt = half ? WtB : WtA;
  const float* bias = half ? biasB : biasA;
  bf16* Out = half ? OutB : OutA;
  if (KMEAN && half && t < 96) colsum[t] = 0.f;
  floatx4 acc[2][6] = {};
  for (int kc = 0; kc < CH; kc += 64) {
    #pragma unroll
    for (int i = 0; i < 4; i++) {
      int rb = (i * 4 + wave) * 8;
      int m = rb + (lane >> 3);
      int u = (lane & 7) ^ (m & 7);
      GLDS16(&A[(size_t)(m0 + m) * CH + kc + u * 8], &As[rb * 64]);
    }
    #pragma unroll
    for (int i = 0; i < 3; i++) {
      int rb = (i * 4 + wave) * 8;
      int n = rb + (lane >> 3);
      int u = (lane & 7) ^ (n & 7);
      GLDS16(&Wt[(size_t)(n0l + n) * CH + kc + u * 8], &Bs[rb * 64]);
    }
    __syncthreads();
    #pragma unroll
    for (int ks = 0; ks < 2; ks++) {
      short8 af[2], bfr[6];
      #pragma unroll
      for (int i = 0; i < 2; i++) {
        int row = wave * 32 + i * 16 + l16;
        af[i] = *(const short8*)&As[row * 64 + ((ks * 4 + quad) ^ (row & 7)) * 8];
      }
      #pragma unroll
      for (int j = 0; j < 6; j++) {
        int row = j * 16 + l16;
        bfr[j] = *(const short8*)&Bs[row * 64 + ((ks * 4 + quad) ^ (row & 7)) * 8];
      }
      #pragma unroll
      for (int i = 0; i < 2; i++)
        #pragma unroll
        for (int j = 0; j < 6; j++)
          acc[i][j] = __builtin_amdgcn_mfma_f32_16x16x32_bf16(af[i], bfr[j], acc[i][j], 0, 0, 0);
    }
    __syncthreads();
  }
  #pragma unroll
  for (int j = 0; j < 6; j++) {
    int nl = n0l + j * 16 + l16;
    float bn = bias[nl];
    float csum = 0.f;
    #pragma unroll
    for (int i = 0; i < 2; i++) {
      #pragma unroll
      for (int r = 0; r < 4; r++) {
        int m = m0 + wave * 32 + i * 16 + quad * 4 + r;
        float v = half ? actf<ACTB>(acc[i][j][r] + bn) : actf<ACTA>(acc[i][j][r] + bn);
        if (KMEAN && half) csum += v;
        Out[(size_t)m * CH + nl] = f2b(v);
      }
    }
    if (KMEAN && half) atomicAdd(&colsum[j * 16 + l16], csum);
  }
  if (KMEAN && half) {
    __syncthreads();
    if (t < 96) {
      int b = m0 >> 12;
      atomicAdd(&KM[b * CH + n0l + t], colsum[t] * (1.f / 4096.f));
    }
  }
}

// ---------------- kv via MFMA: kv[d][e] = sum_n K_rope[n][d] * V[n][e] ----------------
__global__ __launch_bounds__(256) void k_kv(const bf16* __restrict__ k,
                                            const bf16* __restrict__ v,
                                            const float* __restrict__ cosT,
                                            const float* __restrict__ sinT,
                                            float* __restrict__ kv) {
  int bh = blockIdx.x;
  int b = bh / NHEADS, hd = bh % NHEADS;
  int chunk0 = blockIdx.y * 512;
  __shared__ __align__(16) bf16 kst[32][280];
  __shared__ __align__(16) bf16 vst[32][280];
  int t = threadIdx.x;
  int wave = t >> 6, lane = t & 63;
  int quad = lane >> 4, l16 = lane & 15;
  int dh = wave >> 1, eh = wave & 1;
  floatx4 acc = {};
  for (int sub = 0; sub < 2; sub++) {
    int n0 = chunk0 + sub * 256;
    #pragma unroll
    for (int it = 0; it < 4; it++) {
      int idx = t + it * 256;            // 0..1023 = 256 rows x 4 c-groups
      int row = idx >> 2, c0 = (idx & 3) * 8;
      int n = n0 + row;
      size_t gi = ((size_t)(b * HWSZ + n)) * CH + hd * HDIM + c0;
      short8 vv = *(const short8*)&v[gi];
      #pragma unroll
      for (int j = 0; j < 8; j++) vst[c0 + j][row] = ((const bf16*)&vv)[j];
      float4 klo = ld4(&k[gi]);
      float4 khi = ld4(&k[gi + 4]);
      int prb = hd * 16 + (c0 >> 1);
      float cs0 = cosT[(size_t)(prb + 0) * HWSZ + n];
      float sn0 = sinT[(size_t)(prb + 0) * HWSZ + n];
      float cs1 = cosT[(size_t)(prb + 1) * HWSZ + n];
      float sn1 = sinT[(size_t)(prb + 1) * HWSZ + n];
      float cs2 = cosT[(size_t)(prb + 2) * HWSZ + n];
      float sn2 = sinT[(size_t)(prb + 2) * HWSZ + n];
      float cs3 = cosT[(size_t)(prb + 3) * HWSZ + n];
      float sn3 = sinT[(size_t)(prb + 3) * HWSZ + n];
      kst[c0 + 0][row] = f2b(klo.x * cs0 - klo.y * sn0);
      kst[c0 + 1][row] = f2b(klo.x * sn0 + klo.y * cs0);
      kst[c0 + 2][row] = f2b(klo.z * cs1 - klo.w * sn1);
      kst[c0 + 3][row] = f2b(klo.z * sn1 + klo.w * cs1);
      kst[c0 + 4][row] = f2b(khi.x * cs2 - khi.y * sn2);
      kst[c0 + 5][row] = f2b(khi.x * sn2 + khi.y * cs2);
      kst[c0 + 6][row] = f2b(khi.z * cs3 - khi.w * sn3);
      kst[c0 + 7][row] = f2b(khi.z * sn3 + khi.w * cs3);
    }
    __syncthreads();
    #pragma unroll
    for (int ks = 0; ks < 8; ks++) {
      short8 af = *(const short8*)&kst[dh * 16 + l16][ks * 32 + quad * 8];
      short8 bfr = *(const short8*)&vst[eh * 16 + l16][ks * 32 + quad * 8];
      acc = __builtin_amdgcn_mfma_f32_16x16x32_bf16(af, bfr, acc, 0, 0, 0);
    }
    __syncthreads();
  }
  // C/D layout: col = lane&15, row = quad*4 + r  (m89-verified)
  int d = dh * 16 + quad * 4;
  int e = eh * 16 + l16;
  float* dst = kv + (size_t)bh * (HDIM * HDIM) + (size_t)d * HDIM + e;
  const float sc = 1.f / 4096.f;
  #pragma unroll
  for (int r = 0; r < 4; r++) atomicAdd(dst + r * HDIM, acc[r] * sc);
}

// ---------------- attn via MFMA: out = (rope(q) @ kv) * zi ----------------
__global__ __launch_bounds__(256) void k_attn(const bf16* __restrict__ q,
                                              const float* __restrict__ kv,
                                              const float* __restrict__ kmean,
                                              const float* __restrict__ cosT,
                                              const float* __restrict__ sinT,
                                              bf16* __restrict__ attn) {
  int hd = blockIdx.y, b = blockIdx.z;
  int t = threadIdx.x;
  int hw = blockIdx.x * 256 + t;
  int bh = b * NHEADS + hd;
  __shared__ __align__(16) bf16 As[256][40];
  __shared__ __align__(16) bf16 Bs[32][40];
  int wave = t >> 6, lane = t & 63;
  int quad = lane >> 4, l16 = lane & 15;
  // stage kv^T -> Bs[e][d] (bf16)
  {
    int e = t >> 3, d0 = (t & 7) * 4;
    const float* kvp = kv + (size_t)bh * 1024;
    __align__(8) bf16 tmp[4] = {f2b(kvp[(d0 + 0) * 32 + e]), f2b(kvp[(d0 + 1) * 32 + e]),
                                f2b(kvp[(d0 + 2) * 32 + e]), f2b(kvp[(d0 + 3) * 32 + e])};
    *(uint2*)&Bs[e][d0] = *(uint2*)tmp;
  }
  // per-pixel: z (pre-rope) and rope(q) -> As[t][:]
  int pix = b * HWSZ + hw;
  const bf16* qp = q + (size_t)pix * CH + hd * HDIM;
  float qv[32];
  #pragma unroll
  for (int i = 0; i < 32; i++) qv[i] = b2f(qp[i]);
  const float* km = kmean + b * CH + hd * HDIM;
  float z = 1e-6f;
  #pragma unroll
  for (int d = 0; d < 32; d++) z += qv[d] * km[d];
  float zi = 1.f / z;
  __align__(16) bf16 ar[32];
  #pragma unroll
  for (int p = 0; p < 16; p++) {
    float cs = cosT[(size_t)(hd * 16 + p) * HWSZ + hw];
    float sn = sinT[(size_t)(hd * 16 + p) * HWSZ + hw];
    float re = qv[2 * p], im = qv[2 * p + 1];
    ar[2 * p] = f2b(re * cs - im * sn);
    ar[2 * p + 1] = f2b(re * sn + im * cs);
  }
  #pragma unroll
  for (int i = 0; i < 4; i++) *(short8*)&As[t][i * 8] = *(const short8*)&ar[i * 8];
  __syncthreads();
  // MFMA: wave w owns pixels [w*64, w*64+64): 4 m-tiles x 2 n-tiles
  short8 af[4], bfr[2];
  #pragma unroll
  for (int nt = 0; nt < 2; nt++) bfr[nt] = *(const short8*)&Bs[nt * 16 + l16][quad * 8];
  #pragma unroll
  for (int mt = 0; mt < 4; mt++)
    af[mt] = *(const short8*)&As[wave * 64 + mt * 16 + l16][quad * 8];
  floatx4 acc[4][2] = {};
  #pragma unroll
  for (int mt = 0; mt < 4; mt++)
    #pragma unroll
    for (int nt = 0; nt < 2; nt++)
      acc[mt][nt] = __builtin_amdgcn_mfma_f32_16x16x32_bf16(af[mt], bfr[nt], acc[mt][nt], 0, 0, 0);
  __syncthreads();
  // C restage into As: row = pixel (wave-local), col = e
  #pragma unroll
  for (int mt = 0; mt < 4; mt++)
    #pragma unroll
    for (int nt = 0; nt < 2; nt++) {
      int row = wave * 64 + mt * 16 + quad * 4;
      int col = nt * 16 + l16;
      #pragma unroll
      for (int r = 0; r < 4; r++) As[row + r][col] = f2b(acc[mt][nt][r]);
    }
  __syncthreads();
  // each thread: read its own pixel row, scale by in-register zi, coalesced store
  bf16* op = attn + (size_t)pix * CH + hd * HDIM;
  #pragma unroll
  for (int i = 0; i < 4; i++) {
    short8 vv = *(const short8*)&As[t][i * 8];
    __align__(16) bf16 tmp[8];
    #pragma unroll
    for (int j = 0; j < 8; j++) tmp[j] = f2b(b2f(((const bf16*)&vv)[j]) * zi);
    *(short8*)&op[i * 8] = *(const short8*)tmp;
  }
}

extern "C" void kernel_launch(void* const* d_in, const int* in_sizes, int n_in,
                              void* d_out, int out_size, void* d_ws, size_t ws_size,
                              hipStream_t stream) {
  const float* x = (const float*)d_in[0];
  const float* cpe1w = (const float*)d_in[1];
  const float* cpe1b = (const float*)d_in[2];
  const float* n1w = (const float*)d_in[3];
  const float* n1b = (const float*)d_in[4];
  const float* apw = (const float*)d_in[5];
  const float* apb = (const float*)d_in[6];
  const float* ipw = (const float*)d_in[7];
  const float* ipb = (const float*)d_in[8];
  const float* dwcw = (const float*)d_in[9];
  const float* dwcb = (const float*)d_in[10];
  const float* qkw = (const float*)d_in[11];
  const float* qkb = (const float*)d_in[12];
  const float* lepw = (const float*)d_in[13];
  const float* lepb = (const float*)d_in[14];
  const float* opw = (const float*)d_in[15];
  const float* opb = (const float*)d_in[16];
  const float* cpe2w = (const float*)d_in[17];
  const float* cpe2b = (const float*)d_in[18];
  const float* n2w = (const float*)d_in[19];
  const float* n2b = (const float*)d_in[20];
  const float* f1w = (const float*)d_in[21];
  const float* f1b = (const float*)d_in[22];
  const float* f2w = (const float*)d_in[23];
  const float* f2b = (const float*)d_in[24];
  float* out = (float*)d_out;

  float* ws = (float*)d_ws;
  const size_t S = (size_t)NPIX * CH;
  float* FA = ws;                       // fp32: x NHWC -> (bf16 k/attn scratch) -> x3 -> final
  float* FB = ws + S;                   // fp32: x1 -> (bf16 MLP hidden stripes)
  bf16* barena = (bf16*)(ws + 2 * S);
  bf16* b0 = barena;                    // y -> t/v -> y4
  bf16* b1 = barena + S;                // act_res
  bf16* b2 = barena + 2 * S;            // y2 -> q -> x2
  bf16* KB = (bf16*)FA;                 // k, then attn (FA dead between cpe1 and cpe2)
  float* COS = ws + 2 * S + 3 * S / 2;
  float* SIN = COS + (size_t)NPAIR * HWSZ;
  float* KV = SIN + (size_t)NPAIR * HWSZ;
  float* KM = KV + BQ * NHEADS * HDIM * HDIM;
  bf16* WB = (bf16*)(KM + BQ * CH);     // bf16 weight arena (479232 elems)
  bf16* apw16 = WB;
  bf16* ipw16 = WB + 36864;
  bf16* qkw16 = WB + 73728;             // [384][192]; halves at +0 and +36864
  bf16* opw16 = WB + 147456;
  bf16* f1w16 = WB + 184320;
  bf16* f2w16 = WB + 331776;
  bf16* HIDB = (bf16*)FB;

  dim3 tb(32, 8);
  // 0. weights -> bf16 once
  k_wcvt<<<dim3((WTOT / 4 + 255) / 256), dim3(256), 0, stream>>>(
      apw, ipw, qkw, opw, f1w, f2w, WB);
  // 1. transpose input NCHW -> NHWC fp32
  k_transpose_in<<<dim3(6, 128, BQ), tb, 0, stream>>>(x, FA);
  // 2. rope tables [pair][hw]
  k_rope<<<dim3(NPAIR * HWSZ / 256), dim3(256), 0, stream>>>(COS, SIN);
  // 3. x1 = x + cpe1(x); y = LN1(x1)   [fused]
  k_cpe_ln<float><<<dim3(NPIX / 16), dim3(192), 0, stream>>>(FA, cpe1w, cpe1b, n1w, n1b, FB, b0);
  // 4. act_res = silu(act_proj(y)); y2 = in_proj(y)
  k_gemm_dual<1, 0, 0><<<dim3(NPIX / 128, 4), dim3(256), 0, stream>>>(
      b0, apw16, apb, ipw16, ipb, b1, b2, nullptr, CH);
  // 5. t = v = silu(dwc(y2))
  k_dwconv_strip<1><<<dim3(NPIX / 16), dim3(192), 0, stream>>>(b2, dwcw, dwcb, b0);
  // 6. q,k = elu(t @ qk_w^T + qk_b)+1 ; kmean fused into k epilogue
  hipMemsetAsync(KM, 0, (size_t)BQ * CH * sizeof(float), stream);
  k_gemm_dual<2, 2, 1><<<dim3(NPIX / 128, 4), dim3(256), 0, stream>>>(
      b0, qkw16, qkb, qkw16 + CH * CH, qkb + CH, b2, KB, KM, CH);
  // 7. kv accumulate (fused rope, MFMA, 512 rows/block)
  hipMemsetAsync(KV, 0, (size_t)BQ * NHEADS * HDIM * HDIM * sizeof(float), stream);
  k_kv<<<dim3(BQ * NHEADS, 8), dim3(256), 0, stream>>>(KB, b0, COS, SIN, KV);
  // 8. attn = (q_rope @ kv) * z  -> KB (k dead)
  k_attn<<<dim3(HWSZ / 256, NHEADS, BQ), dim3(256), 0, stream>>>(b2, KV, KM, COS, SIN, KB);
  // 9. attn += lepe(v)
  k_dwconv_strip<2><<<dim3(NPIX / 16), dim3(192), 0, stream>>>(b0, lepw, lepb, KB);
  // 10. x2 = x1 + out_proj(attn * act_res)  -> b2 (bf16)
  k_gemm<0, 1, 1, bf16><<<dim3(NPIX / 128, 3), dim3(256), 0, stream>>>(
      KB, b1, opw16, opb, FB, b2, NPIX, CH, CH);
  // 11. x3 = x2 + cpe2(x2); y4 = LN2(x3)   [fused]
  k_cpe_ln<bf16><<<dim3(NPIX / 16), dim3(192), 0, stream>>>(b2, cpe2w, cpe2b, n2w, n2b, FA, b0);
  // 12. MLP in 2 stripes; hidden bf16 stripe lives in FB (x1 dead)
  for (int s = 0; s < 2; s++) {
    size_t off = (size_t)s * (NPIX / 2) * CH;
    k_gemm<3, 0, 0, bf16><<<dim3((NPIX / 2) / 128, HID / 64), dim3(256), 0, stream>>>(
        b0 + off, (const bf16*)nullptr, f1w16, f1b, (const float*)nullptr, HIDB, NPIX / 2, HID, CH);
    k_gemm<0, 0, 1, float><<<dim3((NPIX / 2) / 128, 3), dim3(256), 0, stream>>>(
        HIDB, (const bf16*)nullptr, f2w16, f2b, FA + off, FA + off, NPIX / 2, CH, HID);
  }
  // 13. final transpose NHWC fp32 -> NCHW fp32
  k_transpose_out<<<dim3(6, 128, BQ), tb, 0, stream>>>(FA, out);
}